// Round 14
// baseline (1488.662 us; speedup 1.0000x reference)
//
#include <hip/hip_runtime.h>
#include <hip/hip_bf16.h>

using bf16 = __hip_bfloat16;
typedef __attribute__((ext_vector_type(8))) short short8;   // 8 bf16 (MFMA A/B frag)
typedef __attribute__((ext_vector_type(4))) float f32x4;
typedef __attribute__((ext_vector_type(16))) float f32x16;  // 32x32 MFMA C/D
typedef __attribute__((ext_vector_type(4))) unsigned short u16x4;  // 4 bf16 chunk

#define MFMA32(A, B, C) __builtin_amdgcn_mfma_f32_32x32x16_bf16(A, B, C, 0, 0, 0)

constexpr int Mdim = 512;
constexpr int Ddim = 1024;
constexpr int Hdim = 2048;
constexpr size_t MH = (size_t)Mdim * Hdim;   // 512*2048 (H-space activations)
constexpr size_t KPL4 = MH / 4;              // owner-layout u16x4/f32x4 chunks per plane

constexpr double Hs = 1.0 / 16.0;
// CF[s-1][j]: coefficient (times h) of K_{j+1} in the combination after stage s.
// Row 5 = 5th-order solution weights (also the G-accumulation weights).
constexpr float CF[6][6] = {
    {float(Hs * 1 / 5.), 0.f, 0.f, 0.f, 0.f, 0.f},
    {float(Hs * 3 / 40.), float(Hs * 9 / 40.), 0.f, 0.f, 0.f, 0.f},
    {float(Hs * 44 / 45.), float(-Hs * 56 / 15.), float(Hs * 32 / 9.), 0.f, 0.f, 0.f},
    {float(Hs * 19372 / 6561.), float(-Hs * 25360 / 2187.), float(Hs * 64448 / 6561.),
     float(-Hs * 212 / 729.), 0.f, 0.f},
    {float(Hs * 9017 / 3168.), float(-Hs * 355 / 33.), float(Hs * 46732 / 5247.),
     float(Hs * 49 / 176.), float(-Hs * 5103 / 18656.), 0.f},
    {float(Hs * 35 / 384.), 0.f, float(Hs * 500 / 1113.), float(Hs * 125 / 192.),
     float(-Hs * 2187 / 6784.), float(Hs * 11 / 84.)},
};

__device__ __forceinline__ float tanh_fast(float x) {
  float xc = fminf(fmaxf(x, -15.0f), 15.0f);
  float t = __expf(2.0f * xc);
  return (t - 1.0f) * __builtin_amdgcn_rcpf(t + 1.0f);
}

__device__ __forceinline__ unsigned short f2bf(float x) {
  bf16 b = __float2bfloat16(x);
  return *(unsigned short*)&b;
}
__device__ __forceinline__ float bf2f(unsigned short u) {
  bf16 b = *(bf16*)&u;
  return __bfloat162float(b);
}

__device__ __forceinline__ void gload_lds16(const void* g, void* lds) {
  __builtin_amdgcn_global_load_lds((const __attribute__((address_space(1))) void*)g,
                                   (__attribute__((address_space(3))) void*)lds, 16, 0, 0);
}

enum { M_PLAIN = 0, M_INIT = 1, M_STG = 2, M_FINAL = 3 };

struct GArgs {
  const bf16* A;      // [M][KDIM] bf16 row-major
  const bf16* Bt;     // [NDIM][KDIM] bf16 row-major (B transposed)
  const bf16* Bp;     // frag-packed W21 (stage kernel only)
  const float* b1;    // bias for tanh input [NDIM]
  const float* b2w1;  // b2@W1 [2048]
  const float* xin;   // x f32 (FINAL)
  const float* b2;    // b2 (FINAL)
  float* yW1;         // MH f32, OWNER layout (f32x4 per (tile,q,lane))
  bf16* T;            // [512][2048] bf16 tanh output, row-major (next GEMM's A)
  bf16* K;            // 5 x MH bf16 K_j storage, OWNER layout (u16x4 chunks)
  float* G;           // [512][2048] f32 accumulated CF5-weighted tanh (row-major)
  bf16* Wout;         // PLAIN bf16 output (W21t)
  float* y;           // FINAL f32 output
};

// Shared RK-stage epilogue at owner position (tile,q,lane); C/D 32x32 layout
// (m74/m101): col=lane&31, row=(g*8)+(hi*4)+e with q=(frag<<2)|g.
template <int STAGE>
__device__ __forceinline__ void stage_epilogue(const GArgs& a, f32x4 s, int tile, int q,
                                               int lane, int r0, int c, int NDIM) {
  u16x4* Kq = (u16x4*)a.K;
  const size_t kb = (size_t)(tile * 16 + q) * 64 + lane;
  const float bb = a.b2w1[c];
  float Kv[4], comb[4];
  const f32x4 yv = ((const f32x4*)a.yW1)[kb];
#pragma unroll
  for (int e = 0; e < 4; ++e) Kv[e] = s[e] + bb;
  if constexpr (STAGE <= 5) {
    u16x4 kw;
#pragma unroll
    for (int e = 0; e < 4; ++e) kw[e] = f2bf(Kv[e]);
    Kq[(size_t)(STAGE - 1) * KPL4 + kb] = kw;     // coalesced 8B/lane
  }
#pragma unroll
  for (int e = 0; e < 4; ++e) comb[e] = yv[e] + CF[STAGE - 1][STAGE - 1] * Kv[e];
  if constexpr (STAGE > 1 && CF[STAGE - 1][0] != 0.f) {
    u16x4 kj = Kq[0 * KPL4 + kb];
#pragma unroll
    for (int e = 0; e < 4; ++e) comb[e] += CF[STAGE - 1][0] * bf2f(kj[e]);
  }
  if constexpr (STAGE > 2 && CF[STAGE - 1][1] != 0.f) {
    u16x4 kj = Kq[1 * KPL4 + kb];
#pragma unroll
    for (int e = 0; e < 4; ++e) comb[e] += CF[STAGE - 1][1] * bf2f(kj[e]);
  }
  if constexpr (STAGE > 3 && CF[STAGE - 1][2] != 0.f) {
    u16x4 kj = Kq[2 * KPL4 + kb];
#pragma unroll
    for (int e = 0; e < 4; ++e) comb[e] += CF[STAGE - 1][2] * bf2f(kj[e]);
  }
  if constexpr (STAGE > 4 && CF[STAGE - 1][3] != 0.f) {
    u16x4 kj = Kq[3 * KPL4 + kb];
#pragma unroll
    for (int e = 0; e < 4; ++e) comb[e] += CF[STAGE - 1][3] * bf2f(kj[e]);
  }
  if constexpr (STAGE > 5 && CF[STAGE - 1][4] != 0.f) {
    u16x4 kj = Kq[4 * KPL4 + kb];
#pragma unroll
    for (int e = 0; e < 4; ++e) comb[e] += CF[STAGE - 1][4] * bf2f(kj[e]);
  }
  if constexpr (STAGE == 6) {
    f32x4 cw = {comb[0], comb[1], comb[2], comb[3]};
    ((f32x4*)a.yW1)[kb] = cw;                     // 5th-order yW1 update
  }
  const float bv = a.b1[c];
#pragma unroll
  for (int e = 0; e < 4; ++e) {
    const size_t idx = (size_t)(r0 + e) * NDIM + c;
    const float tv = tanh_fast(comb[e] + bv);
    a.T[idx] = __float2bfloat16(tv);
    if constexpr (STAGE < 6) {
      if constexpr (CF[5][STAGE] != 0.f) a.G[idx] += CF[5][STAGE] * tv;
    } else {
      a.G[idx] += CF[5][0] * tv;                  // T_1-of-next-step contribution
    }
  }
}

// ===== Hot stage kernel: C = T(512x2048) @ W21^T, 64x64 tile, K=2048 =====
// 8 waves, each the full 64x64 tile on a disjoint K=16 slice. B comes DIRECTLY
// from L2 as frag-packed records (1KB coalesced load/wave/frag, 3-slot register
// rotation, distance-2 prefetch) -- NOT through LDS. A keeps the proven LDS
// pipeline: 3x16KB buffers, counted vmcnt(4) ({vmcnt(4); s_barrier; sched_barrier;
// issue B(t+2)+stageA(t+2); ds_read+MFMA(t)}). LDS traffic/iter halves (64->32KB)
// while L2/iter is unchanged (A 16KB staged + B 16KB regs). In-order vmcnt:
// oldest-4 outstanding = B(t)+A(t), so vmcnt(4) releases exactly tile t.
// 8-way K-reduce + owner-layout epilogue identical to the proven r13 structure.
template <int STAGE>
__global__ __launch_bounds__(512, 2) void fused_stage(GArgs a) {
  constexpr int NITER = 16;           // 2048 / BK128
  extern __shared__ char smem_c[];    // 131072: A staging 3x16KB at base; exchange 128KB

  const int tid = threadIdx.x;
  const int lane = tid & 63;
  const int wid = tid >> 6;
  const int l31 = lane & 31;
  const int hi = lane >> 5;

  const int bid = blockIdx.x;
  const int nt = (bid & 7) * 4 + ((bid >> 3) & 3);   // 32 n-tiles, 4 per XCD
  const int mt = bid >> 5;                            // 8 m-tiles
  const int brow = mt * 64, bcol = nt * 64;
  const int tile = mt * 32 + nt;

  // ---- A staging: 64 rows x 16 chunks; thread covers q=tid, q=tid+512 ----
  const int rs0 = tid >> 4;
  const int cgS = (tid & 15) ^ (rs0 & 7);
  const bf16* pA0 = a.A + (size_t)(brow + rs0) * 2048 + cgS * 8;
  const bf16* pA1 = pA0 + (size_t)32 * 2048;
  char* dA = smem_c + tid * 16;

#define STG_A(T_)                                                              \
  {                                                                            \
    const int B_ = ((T_) % 3) * 16384;                                         \
    const int KO_ = (T_)*128;                                                  \
    gload_lds16(pA0 + KO_, dA + B_); gload_lds16(pA1 + KO_, dA + B_ + 8192);   \
  }

  // ---- B frag-packed pointers: record (nt32, kk, lane) = 8 bf16; this wave's
  // k-slice per iter t is kk = t*8 + wid -> element offset t*4096.
  const bf16* bp0 = a.Bp + ((size_t)(nt * 2) * 128 + wid) * 512 + lane * 8;
  const bf16* bp1 = bp0 + (size_t)128 * 512;

  // ---- A ds_read: row l31, chunk (wid*2+hi)^(l31&7) ----
  const int xo = l31 * 256 + (((wid * 2 + hi) ^ (l31 & 7)) << 4);
  const char* rA = smem_c + xo;            // + mf*8192 + buf*16384

  f32x16 acc[2][2] = {};
  short8 bB[3][2];

  bB[0][0] = *(const short8*)(bp0);
  bB[0][1] = *(const short8*)(bp1);
  STG_A(0)
  bB[1][0] = *(const short8*)(bp0 + 4096);
  bB[1][1] = *(const short8*)(bp1 + 4096);
  STG_A(1)

#pragma unroll
  for (int t = 0; t < NITER; ++t) {
    if (t < NITER - 1) asm volatile("s_waitcnt vmcnt(4)" ::: "memory");
    else               asm volatile("s_waitcnt vmcnt(0)" ::: "memory");
    __builtin_amdgcn_s_barrier();
    __builtin_amdgcn_sched_barrier(0);
    if (t + 2 < NITER) {
      bB[(t + 2) % 3][0] = *(const short8*)(bp0 + (t + 2) * 4096);
      bB[(t + 2) % 3][1] = *(const short8*)(bp1 + (t + 2) * 4096);
      STG_A(t + 2)
    }
    const int BO = (t % 3) * 16384;
    short8 af0 = *(const short8*)(rA + BO);
    short8 af1 = *(const short8*)(rA + BO + 8192);
    __builtin_amdgcn_s_setprio(1);
    acc[0][0] = MFMA32(af0, bB[t % 3][0], acc[0][0]);
    acc[0][1] = MFMA32(af0, bB[t % 3][1], acc[0][1]);
    acc[1][0] = MFMA32(af1, bB[t % 3][0], acc[1][0]);
    acc[1][1] = MFMA32(af1, bB[t % 3][1], acc[1][1]);
    __builtin_amdgcn_s_setprio(0);
  }
#undef STG_A

  // ---- 8-way K-reduce via owner distribution (128KB exchange, aliases staging) ----
  __syncthreads();
#pragma unroll
  for (int mf = 0; mf < 2; ++mf)
#pragma unroll
    for (int nf = 0; nf < 2; ++nf)
#pragma unroll
      for (int g = 0; g < 4; ++g) {
        f32x4 v = {acc[mf][nf][g * 4 + 0], acc[mf][nf][g * 4 + 1],
                   acc[mf][nf][g * 4 + 2], acc[mf][nf][g * 4 + 3]};
        *(f32x4*)(smem_c + ((((mf * 2 + nf) * 4 + g) * 8 + wid) << 10) + lane * 16) = v;
      }
  __syncthreads();

#pragma unroll
  for (int of = 0; of < 2; ++of) {
    const int q = wid * 2 + of;
    f32x4 s = {};
#pragma unroll
    for (int w = 0; w < 8; ++w)
      s += *(const f32x4*)(smem_c + (((q * 8 + w) << 10)) + lane * 16);
    const int p = q >> 2, g = q & 3;
    const int mf = p >> 1, nf = p & 1;
    const int c = bcol + nf * 32 + l31;
    const int r0 = brow + mf * 32 + g * 8 + hi * 4;
    stage_epilogue<STAGE>(a, s, tile, q, lane, r0, c, Hdim);
  }
}

// ===== Setup / init / final kernel (round-13 proven structure, unchanged) =====
template <int MODE, int STAGE, int NDIM, int KDIM>
__global__ __launch_bounds__(512, 2) void fused_gemm(GArgs a) {
  constexpr int BK = 128;
  constexpr int NITER = KDIM / BK;
  constexpr int NP = (NDIM / 64) / 8;

  extern __shared__ char smem_c[];

  const int tid = threadIdx.x;
  const int lane = tid & 63;
  const int wid = tid >> 6;
  const int l31 = lane & 31;
  const int hi = lane >> 5;

  const int bid = blockIdx.x;
  const int nt = (bid & 7) * NP + ((bid >> 3) % NP);
  const int mt = (bid >> 3) / NP;
  const int brow = mt * 64, bcol = nt * 64;
  const int tile = mt * (NDIM / 64) + nt;

  const int rs0 = tid >> 4;
  const int cgS = (tid & 15) ^ (rs0 & 7);
  const bf16* pA0 = a.A + (size_t)(brow + rs0) * KDIM + cgS * 8;
  const bf16* pA1 = pA0 + (size_t)32 * KDIM;
  const bf16* pB0 = a.Bt + (size_t)(bcol + rs0) * KDIM + cgS * 8;
  const bf16* pB1 = pB0 + (size_t)32 * KDIM;
  char* dA = smem_c + tid * 16;
  char* dB = smem_c + 16384 + tid * 16;

#define STAGE_TILE(T_)                                                       \
  {                                                                          \
    const int B_ = ((T_) % 3) * 32768;                                       \
    const int KO_ = (T_)*BK;                                                 \
    gload_lds16(pA0 + KO_, dA + B_); gload_lds16(pA1 + KO_, dA + B_ + 8192); \
    gload_lds16(pB0 + KO_, dB + B_); gload_lds16(pB1 + KO_, dB + B_ + 8192); \
  }

  const int xo = l31 * 256 + (((wid * 2 + hi) ^ (l31 & 7)) << 4);
  const char* rA = smem_c + xo;
  const char* rB = smem_c + 16384 + xo;

  f32x16 acc[2][2] = {};

  STAGE_TILE(0)
  STAGE_TILE(1)

#pragma unroll
  for (int t = 0; t < NITER; ++t) {
    if (t < NITER - 1) asm volatile("s_waitcnt vmcnt(4)" ::: "memory");
    else               asm volatile("s_waitcnt vmcnt(0)" ::: "memory");
    __builtin_amdgcn_s_barrier();
    __builtin_amdgcn_sched_barrier(0);
    if (t + 2 < NITER) STAGE_TILE(t + 2)
    const int BO = (t % 3) * 32768;
    short8 af0 = *(const short8*)(rA + BO);
    short8 af1 = *(const short8*)(rA + BO + 8192);
    short8 bw0 = *(const short8*)(rB + BO);
    short8 bw1 = *(const short8*)(rB + BO + 8192);
    __builtin_amdgcn_s_setprio(1);
    acc[0][0] = MFMA32(af0, bw0, acc[0][0]);
    acc[0][1] = MFMA32(af0, bw1, acc[0][1]);
    acc[1][0] = MFMA32(af1, bw0, acc[1][0]);
    acc[1][1] = MFMA32(af1, bw1, acc[1][1]);
    __builtin_amdgcn_s_setprio(0);
  }
#undef STAGE_TILE

  __syncthreads();
#pragma unroll
  for (int mf = 0; mf < 2; ++mf)
#pragma unroll
    for (int nf = 0; nf < 2; ++nf)
#pragma unroll
      for (int g = 0; g < 4; ++g) {
        f32x4 v = {acc[mf][nf][g * 4 + 0], acc[mf][nf][g * 4 + 1],
                   acc[mf][nf][g * 4 + 2], acc[mf][nf][g * 4 + 3]};
        *(f32x4*)(smem_c + ((((mf * 2 + nf) * 4 + g) * 8 + wid) << 10) + lane * 16) = v;
      }
  __syncthreads();

#pragma unroll
  for (int of = 0; of < 2; ++of) {
    const int q = wid * 2 + of;
    f32x4 s = {};
#pragma unroll
    for (int w = 0; w < 8; ++w)
      s += *(const f32x4*)(smem_c + (((q * 8 + w) << 10)) + lane * 16);

    const int p = q >> 2, g = q & 3;
    const int mf = p >> 1, nf = p & 1;
    const int c = bcol + nf * 32 + l31;
    const int r0 = brow + mf * 32 + g * 8 + hi * 4;
    if constexpr (MODE == M_PLAIN) {
#pragma unroll
      for (int e = 0; e < 4; ++e) a.Wout[(size_t)(r0 + e) * NDIM + c] = __float2bfloat16(s[e]);
    } else if constexpr (MODE == M_INIT) {
      ((f32x4*)a.yW1)[(size_t)(tile * 16 + q) * 64 + lane] = s;
      const float bv = a.b1[c];
#pragma unroll
      for (int e = 0; e < 4; ++e) {
        const size_t idx = (size_t)(r0 + e) * NDIM + c;
        const float tv = tanh_fast(s[e] + bv);
        a.T[idx] = __float2bfloat16(tv);
        a.G[idx] = CF[5][0] * tv;
      }
    } else {  // M_FINAL
      const float bv = a.b2[c];
#pragma unroll
      for (int e = 0; e < 4; ++e) {
        const size_t idx = (size_t)(r0 + e) * NDIM + c;
        a.y[idx] = a.xin[idx] + s[e] + bv;
      }
    }
  }
}

// W21t [2048][2048] row-major -> frag-packed W21p: record (nt32,kk,lane) j-th elem
// = W21t[nt32*32 + (lane&31)][kk*16 + (lane>>5)*8 + j]  (one-time, 8MB)
__global__ void pack_w21(const bf16* __restrict__ in, bf16* __restrict__ out) {
  const int t = blockIdx.x * 256 + threadIdx.x;   // < 64*128*64
  const int lane = t & 63;
  const int kk = (t >> 6) & 127;
  const int nt32 = t >> 13;
  const bf16* src = in + (size_t)(nt32 * 32 + (lane & 31)) * 2048 + kk * 16 + (lane >> 5) * 8;
  *(short8*)(out + (size_t)t * 8) = *(const short8*)src;
}

// fp32 [R][C] -> bf16 [C][R]
__global__ void transpose_to_bf16(const float* __restrict__ in, bf16* __restrict__ out, int R,
                                  int C) {
  __shared__ float t[32][33];
  const int c0 = blockIdx.x * 32, r0 = blockIdx.y * 32;
#pragma unroll
  for (int i = threadIdx.y; i < 32; i += 8)
    t[i][threadIdx.x] = in[(size_t)(r0 + i) * C + c0 + threadIdx.x];
  __syncthreads();
#pragma unroll
  for (int i = threadIdx.y; i < 32; i += 8)
    out[(size_t)(c0 + i) * R + r0 + threadIdx.x] = __float2bfloat16(t[threadIdx.x][i]);
}

// fp32 -> bf16 elementwise (4 per thread)
__global__ void cast_bf16(const float* __restrict__ in, bf16* __restrict__ out, int n4) {
  int i = blockIdx.x * 256 + threadIdx.x;
  if (i < n4) {
    float4 v = *(const float4*)(in + i * 4);
    bf16* o = out + i * 4;
    o[0] = __float2bfloat16(v.x); o[1] = __float2bfloat16(v.y);
    o[2] = __float2bfloat16(v.z); o[3] = __float2bfloat16(v.w);
  }
}

// b2w1[h'] = sum_d b2[d] * W1[d][h']   (W1 f32 [1024][2048])
__global__ void b2w1_kernel(const float* __restrict__ b2, const float* __restrict__ W1,
                            float* __restrict__ out) {
  const int h = blockIdx.x * 256 + threadIdx.x;
  float s = 0.f;
  for (int d = 0; d < Ddim; ++d) s += b2[d] * W1[(size_t)d * Hdim + h];
  out[h] = s;
}

extern "C" void kernel_launch(void* const* d_in, const int* in_sizes, int n_in, void* d_out,
                              int out_size, void* d_ws, size_t ws_size, hipStream_t stream) {
  const float* x = (const float*)d_in[0];
  const float* W1 = (const float*)d_in[1];
  const float* b1 = (const float*)d_in[2];
  const float* W2 = (const float*)d_in[3];
  const float* b2 = (const float*)d_in[4];
  float* y = (float*)d_out;

  char* ws = (char*)d_ws;
  bf16* W1t = (bf16*)(ws + 0);                  // [2048][1024] bf16, 4 MB   (W1^T)
  bf16* W2bf = (bf16*)(ws + (4ull << 20));      // [2048][1024] bf16, 4 MB   (W2 rm)
  bf16* W2t = (bf16*)(ws + (8ull << 20));       // [1024][2048] bf16, 4 MB   (W2^T)
  bf16* W21t = (bf16*)(ws + (12ull << 20));     // [2048][2048] bf16, 8 MB   ((W2@W1)^T)
  bf16* xbf = (bf16*)(ws + (20ull << 20));      // [512][1024] bf16, 1 MB
  bf16* Tbuf = (bf16*)(ws + (21ull << 20));     // [512][2048] bf16, 2 MB
  bf16* Kbuf = (bf16*)(ws + (23ull << 20));     // 5 x MH bf16 (owner layout), 10 MB
  bf16* Gbf = (bf16*)(ws + (33ull << 20));      // [512][2048] bf16, 2 MB
  float* yW1 = (float*)(ws + (35ull << 20));    // MH f32 (owner layout), 4 MB
  float* Gacc = (float*)(ws + (39ull << 20));   // [512][2048] f32, 4 MB
  float* b2w1 = (float*)(ws + (43ull << 20));   // [2048] f32
  bf16* W21p = (bf16*)(ws + (44ull << 20));     // frag-packed W21, 8 MB

  GArgs a = {};
  a.b1 = b1; a.b2w1 = b2w1; a.xin = x; a.b2 = b2;
  a.yW1 = yW1; a.T = Tbuf; a.K = Kbuf; a.G = Gacc; a.y = y; a.Bp = W21p;

  constexpr int SMEM = 131072;
  hipFuncSetAttribute((const void*)&fused_gemm<M_PLAIN, 0, Hdim, 1024>,
                      hipFuncAttributeMaxDynamicSharedMemorySize, SMEM);
  hipFuncSetAttribute((const void*)&fused_gemm<M_INIT, 0, Hdim, 1024>,
                      hipFuncAttributeMaxDynamicSharedMemorySize, SMEM);
  hipFuncSetAttribute((const void*)&fused_gemm<M_FINAL, 0, Ddim, Hdim>,
                      hipFuncAttributeMaxDynamicSharedMemorySize, SMEM);
  hipFuncSetAttribute((const void*)&fused_stage<1>, hipFuncAttributeMaxDynamicSharedMemorySize,
                      SMEM);
  hipFuncSetAttribute((const void*)&fused_stage<2>, hipFuncAttributeMaxDynamicSharedMemorySize,
                      SMEM);
  hipFuncSetAttribute((const void*)&fused_stage<3>, hipFuncAttributeMaxDynamicSharedMemorySize,
                      SMEM);
  hipFuncSetAttribute((const void*)&fused_stage<4>, hipFuncAttributeMaxDynamicSharedMemorySize,
                      SMEM);
  hipFuncSetAttribute((const void*)&fused_stage<5>, hipFuncAttributeMaxDynamicSharedMemorySize,
                      SMEM);
  hipFuncSetAttribute((const void*)&fused_stage<6>, hipFuncAttributeMaxDynamicSharedMemorySize,
                      SMEM);

  // ---- setup (one-time) ----
  transpose_to_bf16<<<dim3(Hdim / 32, Ddim / 32), dim3(32, 8), 0, stream>>>(W1, W1t, Ddim, Hdim);
  transpose_to_bf16<<<dim3(Ddim / 32, Hdim / 32), dim3(32, 8), 0, stream>>>(W2, W2t, Hdim, Ddim);
  cast_bf16<<<(Hdim * Ddim / 4 + 255) / 256, 256, 0, stream>>>(W2, W2bf, Hdim * Ddim / 4);
  cast_bf16<<<(Mdim * Ddim / 4 + 255) / 256, 256, 0, stream>>>(x, xbf, Mdim * Ddim / 4);
  b2w1_kernel<<<Hdim / 256, 256, 0, stream>>>(b2, W1, b2w1);

  // W21t[h'][h] = sum_d W1[d,h']*W2[h,d]  : A=W1t [2048][1024], Bt=W2bf [2048][1024]
  {
    GArgs p = a; p.A = W1t; p.Bt = W2bf; p.Wout = W21t;
    fused_gemm<M_PLAIN, 0, Hdim, 1024><<<32 * 32, 512, SMEM, stream>>>(p);
  }
  pack_w21<<<64 * 128 * 64 / 256, 256, 0, stream>>>(W21t, W21p);
  // init: yW1 = x@W1 (owner layout) ; T1 = tanh(+b1) ; G = CF5[0]*tanh
  {
    GArgs p = a; p.A = xbf; p.Bt = W1t;
    fused_gemm<M_INIT, 0, Hdim, 1024><<<8 * 32, 512, SMEM, stream>>>(p);
  }

  // ---- 16 RK steps, one H-space GEMM per stage (skip last step's stage 6) ----
  GArgs sg = a; sg.A = Tbuf;
  for (int step = 0; step < 16; ++step) {
    fused_stage<1><<<256, 512, SMEM, stream>>>(sg);
    fused_stage<2><<<256, 512, SMEM, stream>>>(sg);
    fused_stage<3><<<256, 512, SMEM, stream>>>(sg);
    fused_stage<4><<<256, 512, SMEM, stream>>>(sg);
    fused_stage<5><<<256, 512, SMEM, stream>>>(sg);
    if (step < 15)
      fused_stage<6><<<256, 512, SMEM, stream>>>(sg);
  }

  // ---- final: y = x + Gbf@W2 + b2 ----
  cast_bf16<<<(int)(MH / 4 + 255) / 256, 256, 0, stream>>>(Gacc, Gbf, (int)(MH / 4));
  {
    GArgs p = a; p.A = Gbf; p.Bt = W2t;
    fused_gemm<M_FINAL, 0, Ddim, Hdim><<<8 * 16, 512, SMEM, stream>>>(p);
  }
}

// Round 15
// 1272.667 us; speedup vs baseline: 1.1697x; 1.1697x over previous
//
#include <hip/hip_runtime.h>
#include <hip/hip_bf16.h>

using bf16 = __hip_bfloat16;
typedef __attribute__((ext_vector_type(8))) short short8;   // 8 bf16 (MFMA A/B frag)
typedef __attribute__((ext_vector_type(4))) float f32x4;
typedef __attribute__((ext_vector_type(16))) float f32x16;  // 32x32 MFMA C/D
typedef __attribute__((ext_vector_type(4))) unsigned short u16x4;  // 4 bf16 chunk

#define MFMA32(A, B, C) __builtin_amdgcn_mfma_f32_32x32x16_bf16(A, B, C, 0, 0, 0)

constexpr int Mdim = 512;
constexpr int Ddim = 1024;
constexpr int Hdim = 2048;
constexpr size_t MH = (size_t)Mdim * Hdim;   // 512*2048 (H-space activations)
constexpr size_t KPL4 = MH / 4;              // owner-layout chunks per plane

constexpr double Hs = 1.0 / 16.0;
// CF[s-1][j]: coefficient (times h) of K_{j+1} in the combination after stage s.
// Row 5 = 5th-order solution weights (also the G-accumulation weights).
constexpr float CF[6][6] = {
    {float(Hs * 1 / 5.), 0.f, 0.f, 0.f, 0.f, 0.f},
    {float(Hs * 3 / 40.), float(Hs * 9 / 40.), 0.f, 0.f, 0.f, 0.f},
    {float(Hs * 44 / 45.), float(-Hs * 56 / 15.), float(Hs * 32 / 9.), 0.f, 0.f, 0.f},
    {float(Hs * 19372 / 6561.), float(-Hs * 25360 / 2187.), float(Hs * 64448 / 6561.),
     float(-Hs * 212 / 729.), 0.f, 0.f},
    {float(Hs * 9017 / 3168.), float(-Hs * 355 / 33.), float(Hs * 46732 / 5247.),
     float(Hs * 49 / 176.), float(-Hs * 5103 / 18656.), 0.f},
    {float(Hs * 35 / 384.), 0.f, float(Hs * 500 / 1113.), float(Hs * 125 / 192.),
     float(-Hs * 2187 / 6784.), float(Hs * 11 / 84.)},
};

__device__ __forceinline__ float tanh_fast(float x) {
  float xc = fminf(fmaxf(x, -15.0f), 15.0f);
  float t = __expf(2.0f * xc);
  return (t - 1.0f) * __builtin_amdgcn_rcpf(t + 1.0f);
}

__device__ __forceinline__ unsigned short f2bf(float x) {
  bf16 b = __float2bfloat16(x);
  return *(unsigned short*)&b;
}
__device__ __forceinline__ float bf2f(unsigned short u) {
  bf16 b = *(bf16*)&u;
  return __bfloat162float(b);
}

__device__ __forceinline__ void gload_lds16(const void* g, void* lds) {
  __builtin_amdgcn_global_load_lds((const __attribute__((address_space(1))) void*)g,
                                   (__attribute__((address_space(3))) void*)lds, 16, 0, 0);
}

enum { M_PLAIN = 0, M_INIT = 1, M_STG = 2, M_FINAL = 3 };

struct GArgs {
  const bf16* A;      // [M][KDIM] bf16 row-major
  const bf16* Bt;     // [NDIM][KDIM] bf16 row-major (B transposed)
  const float* b1;    // bias for tanh input [NDIM]
  const float* b2w1;  // b2@W1 [2048]
  const float* xin;   // x f32 (FINAL)
  const float* b2;    // b2 (FINAL)
  float* yW1;         // MH f32, OWNER layout (f32x4 per (tile,q,lane))
  bf16* T;            // [512][2048] bf16 tanh output, row-major (next GEMM's A)
  bf16* K;            // 5 x MH bf16 K_j storage, OWNER layout (u16x4 chunks)
  unsigned short* G;  // MH bf16 accumulated CF5-weighted tanh, OWNER layout
  bf16* Wout;         // PLAIN bf16 output (W21t)
  float* y;           // FINAL f32 output
};

// C = A(M x KDIM) * Bt^T; 64x64 block tile; 8 waves, EACH with the full 64x64 tile
// (2x2 frags of mfma_32x32x16_bf16) on a disjoint K=16 slice => every staged LDS
// byte is ds_read exactly ONCE. BK=128, THREE 32KB buffers, prefetch distance 2,
// counted vmcnt(4): {vmcnt(4); s_barrier; sched_barrier; stage(t+2); read+MFMA(t)}
// -- no full drain in steady state. 8-way K-reduce via 128KB LDS exchange; owner
// (wid*2+of) sums 8 and runs the epilogue => all 512 threads active.
// Owner layouts: yW1/K/G are internal scratch only touched at owner positions ->
// (tile,q,lane) f32x4/u16x4 chunks, coalesced single-instruction access. G is
// bf16 (halves the largest epilogue traffic term: 16->8 MB/stage RMW).
// 32x32 C/D layout (m74/m101): col=lane&31, row=(g*8)+(hi*4)+e with q=(frag<<2)|g.
// XOR swizzle (involution on 16B chunks, source-side) for ds_read bank spread.
// Grid XCD-swizzled: NP n-tiles per XCD share a weight slice (L2-resident).
template <int MODE, int STAGE, int NDIM, int KDIM>
__global__ __launch_bounds__(512, 2) void fused_gemm(GArgs a) {
  constexpr int BK = 128;
  constexpr int NITER = KDIM / BK;
  constexpr int NP = (NDIM / 64) / 8;

  extern __shared__ char smem_c[];  // 131072: staging 3x32KB; exchange 128KB after

  const int tid = threadIdx.x;
  const int lane = tid & 63;
  const int wid = tid >> 6;          // K-slice id (K=16 within BK=128)
  const int l31 = lane & 31;
  const int hi = lane >> 5;

  const int bid = blockIdx.x;
  const int nt = (bid & 7) * NP + ((bid >> 3) % NP);
  const int mt = (bid >> 3) / NP;
  const int brow = mt * 64, bcol = nt * 64;
  const int tile = mt * (NDIM / 64) + nt;   // stable across all dispatches

  // ---- staging: per matrix 64 rows x 16 chunks(16B) = 1024 chunks; thread covers
  // q = tid (rows 0..31) and q = tid+512 (rows 32..63) at fixed swizzled source
  // chunk (cs^(r&7); r&7 invariant under +32). LDS dest linear (gload constraint).
  const int rs0 = tid >> 4;
  const int cgS = (tid & 15) ^ (rs0 & 7);
  const bf16* pA0 = a.A + (size_t)(brow + rs0) * KDIM + cgS * 8;
  const bf16* pA1 = pA0 + (size_t)32 * KDIM;
  const bf16* pB0 = a.Bt + (size_t)(bcol + rs0) * KDIM + cgS * 8;
  const bf16* pB1 = pB0 + (size_t)32 * KDIM;
  char* dA = smem_c + tid * 16;            // A region [0,16K) of each buffer
  char* dB = smem_c + 16384 + tid * 16;    // B region [16K,32K)

#define STAGE_TILE(T_)                                                       \
  {                                                                          \
    const int B_ = ((T_) % 3) * 32768;                                       \
    const int KO_ = (T_)*BK;                                                 \
    gload_lds16(pA0 + KO_, dA + B_); gload_lds16(pA1 + KO_, dA + B_ + 8192); \
    gload_lds16(pB0 + KO_, dB + B_); gload_lds16(pB1 + KO_, dB + B_ + 8192); \
  }

  // ---- ds_read per-lane offset: row = l31, chunk = (wid*2 + hi) ^ (row&7).
  const int xo = l31 * 256 + (((wid * 2 + hi) ^ (l31 & 7)) << 4);
  const char* rA = smem_c + xo;              // + mf*8192 + buf
  const char* rB = smem_c + 16384 + xo;      // + nf*8192 + buf

  f32x16 acc[2][2] = {};   // [mf][nf] 32x32 frags, this wave's K-slice partial

  STAGE_TILE(0)
  STAGE_TILE(1)

#pragma unroll
  for (int t = 0; t < NITER; ++t) {
    if (t < NITER - 1) asm volatile("s_waitcnt vmcnt(4)" ::: "memory");
    else               asm volatile("s_waitcnt vmcnt(0)" ::: "memory");
    __builtin_amdgcn_s_barrier();
    __builtin_amdgcn_sched_barrier(0);
    if (t + 2 < NITER) STAGE_TILE(t + 2)
    const int BO = (t % 3) * 32768;
    short8 af0 = *(const short8*)(rA + BO);
    short8 af1 = *(const short8*)(rA + BO + 8192);
    short8 bw0 = *(const short8*)(rB + BO);
    short8 bw1 = *(const short8*)(rB + BO + 8192);
    __builtin_amdgcn_s_setprio(1);
    acc[0][0] = MFMA32(af0, bw0, acc[0][0]);
    acc[0][1] = MFMA32(af0, bw1, acc[0][1]);
    acc[1][0] = MFMA32(af1, bw0, acc[1][0]);
    acc[1][1] = MFMA32(af1, bw1, acc[1][1]);
    __builtin_amdgcn_s_setprio(0);
  }
#undef STAGE_TILE

  // ---- 8-way K-reduce via owner distribution: chunk q = (mf*2+nf)*4 + g ----
  __syncthreads();
#pragma unroll
  for (int mf = 0; mf < 2; ++mf)
#pragma unroll
    for (int nf = 0; nf < 2; ++nf)
#pragma unroll
      for (int g = 0; g < 4; ++g) {
        f32x4 v = {acc[mf][nf][g * 4 + 0], acc[mf][nf][g * 4 + 1],
                   acc[mf][nf][g * 4 + 2], acc[mf][nf][g * 4 + 3]};
        *(f32x4*)(smem_c + ((((mf * 2 + nf) * 4 + g) * 8 + wid) << 10) + lane * 16) = v;
      }
  __syncthreads();

#pragma unroll
  for (int of = 0; of < 2; ++of) {
    const int q = wid * 2 + of;        // owned chunk 0..15
    f32x4 s = {};
#pragma unroll
    for (int w = 0; w < 8; ++w)
      s += *(const f32x4*)(smem_c + (((q * 8 + w) << 10)) + lane * 16);

    // Epilogue (all 512 threads). q -> frag p=q>>2 (mf=p>>1, nf=p&1), reg-group g=q&3.
    const int p = q >> 2, g = q & 3;
    const int mf = p >> 1, nf = p & 1;
    const int c = bcol + nf * 32 + l31;
    const int r0 = brow + mf * 32 + g * 8 + hi * 4;   // rows r0..r0+3
    const size_t kb = (size_t)(tile * 16 + q) * 64 + lane;  // owner chunk index
    if constexpr (MODE == M_PLAIN) {
#pragma unroll
      for (int e = 0; e < 4; ++e) a.Wout[(size_t)(r0 + e) * NDIM + c] = __float2bfloat16(s[e]);
    } else if constexpr (MODE == M_INIT) {
      ((f32x4*)a.yW1)[kb] = s;
      const float bv = a.b1[c];
      float tv[4];
#pragma unroll
      for (int e = 0; e < 4; ++e) {
        tv[e] = tanh_fast(s[e] + bv);
        a.T[(size_t)(r0 + e) * NDIM + c] = __float2bfloat16(tv[e]);
      }
      u16x4 gw;
#pragma unroll
      for (int e = 0; e < 4; ++e) gw[e] = f2bf(CF[5][0] * tv[e]);
      ((u16x4*)a.G)[kb] = gw;
    } else if constexpr (MODE == M_STG) {
      u16x4* Kq = (u16x4*)a.K;
      const float bb = a.b2w1[c];
      float Kv[4], comb[4];
      const f32x4 yv = ((const f32x4*)a.yW1)[kb];
#pragma unroll
      for (int e = 0; e < 4; ++e) Kv[e] = s[e] + bb;
      if constexpr (STAGE <= 5) {
        u16x4 kw;
#pragma unroll
        for (int e = 0; e < 4; ++e) kw[e] = f2bf(Kv[e]);
        Kq[(size_t)(STAGE - 1) * KPL4 + kb] = kw;     // coalesced 8B/lane
      }
#pragma unroll
      for (int e = 0; e < 4; ++e) comb[e] = yv[e] + CF[STAGE - 1][STAGE - 1] * Kv[e];
      if constexpr (STAGE > 1 && CF[STAGE - 1][0] != 0.f) {
        u16x4 kj = Kq[0 * KPL4 + kb];
#pragma unroll
        for (int e = 0; e < 4; ++e) comb[e] += CF[STAGE - 1][0] * bf2f(kj[e]);
      }
      if constexpr (STAGE > 2 && CF[STAGE - 1][1] != 0.f) {
        u16x4 kj = Kq[1 * KPL4 + kb];
#pragma unroll
        for (int e = 0; e < 4; ++e) comb[e] += CF[STAGE - 1][1] * bf2f(kj[e]);
      }
      if constexpr (STAGE > 3 && CF[STAGE - 1][2] != 0.f) {
        u16x4 kj = Kq[2 * KPL4 + kb];
#pragma unroll
        for (int e = 0; e < 4; ++e) comb[e] += CF[STAGE - 1][2] * bf2f(kj[e]);
      }
      if constexpr (STAGE > 4 && CF[STAGE - 1][3] != 0.f) {
        u16x4 kj = Kq[3 * KPL4 + kb];
#pragma unroll
        for (int e = 0; e < 4; ++e) comb[e] += CF[STAGE - 1][3] * bf2f(kj[e]);
      }
      if constexpr (STAGE > 5 && CF[STAGE - 1][4] != 0.f) {
        u16x4 kj = Kq[4 * KPL4 + kb];
#pragma unroll
        for (int e = 0; e < 4; ++e) comb[e] += CF[STAGE - 1][4] * bf2f(kj[e]);
      }
      if constexpr (STAGE == 6) {
        f32x4 cw = {comb[0], comb[1], comb[2], comb[3]};
        ((f32x4*)a.yW1)[kb] = cw;                     // 5th-order yW1 update
      }
      const float bv = a.b1[c];
      float tv[4];
#pragma unroll
      for (int e = 0; e < 4; ++e) {
        tv[e] = tanh_fast(comb[e] + bv);
        a.T[(size_t)(r0 + e) * NDIM + c] = __float2bfloat16(tv[e]);
      }
      constexpr float GW = (STAGE < 6) ? CF[5][STAGE] : CF[5][0];
      if constexpr (GW != 0.f) {
        u16x4 gv = ((const u16x4*)a.G)[kb];           // coalesced bf16 RMW
#pragma unroll
        for (int e = 0; e < 4; ++e) gv[e] = f2bf(bf2f(gv[e]) + GW * tv[e]);
        ((u16x4*)a.G)[kb] = gv;
      }
    } else {  // M_FINAL
      const float bv = a.b2[c];
#pragma unroll
      for (int e = 0; e < 4; ++e) {
        const size_t idx = (size_t)(r0 + e) * NDIM + c;
        a.y[idx] = a.xin[idx] + s[e] + bv;
      }
    }
  }
}

// Owner-layout bf16 G -> row-major bf16 (for final GEMM's A staging). One thread
// per (row, 8-col group); writes 16B contiguous.
__global__ void gcvt(const unsigned short* __restrict__ Gown, bf16* __restrict__ out) {
  const int t = blockIdx.x * 256 + threadIdx.x;   // 512*256 = 131072 threads
  const int row = t >> 8;
  const int c0 = (t & 255) * 8;
  const int mt = row >> 6, rm = row & 63;
  const int mf = rm >> 5, g = (rm >> 3) & 3, hi = (rm >> 2) & 1, e = rm & 3;
  const int nt = c0 >> 6, cn = c0 & 63;
  const int nf = cn >> 5;
  const int q = (mf * 2 + nf) * 4 + g;
  const size_t base = ((size_t)((mt * 32 + nt) * 16 + q) * 64 + hi * 32 + (cn & 31)) * 4 + e;
  bf16 tmp[8];
#pragma unroll
  for (int j = 0; j < 8; ++j) {
    unsigned short u = Gown[base + j * 4];
    tmp[j] = *(bf16*)&u;
  }
  *(short8*)(out + (size_t)row * 2048 + c0) = *(short8*)tmp;
}

// fp32 [R][C] -> bf16 [C][R]
__global__ void transpose_to_bf16(const float* __restrict__ in, bf16* __restrict__ out, int R,
                                  int C) {
  __shared__ float t[32][33];
  const int c0 = blockIdx.x * 32, r0 = blockIdx.y * 32;
#pragma unroll
  for (int i = threadIdx.y; i < 32; i += 8)
    t[i][threadIdx.x] = in[(size_t)(r0 + i) * C + c0 + threadIdx.x];
  __syncthreads();
#pragma unroll
  for (int i = threadIdx.y; i < 32; i += 8)
    out[(size_t)(c0 + i) * R + r0 + threadIdx.x] = __float2bfloat16(t[threadIdx.x][i]);
}

// fp32 -> bf16 elementwise (4 per thread)
__global__ void cast_bf16(const float* __restrict__ in, bf16* __restrict__ out, int n4) {
  int i = blockIdx.x * 256 + threadIdx.x;
  if (i < n4) {
    float4 v = *(const float4*)(in + i * 4);
    bf16* o = out + i * 4;
    o[0] = __float2bfloat16(v.x); o[1] = __float2bfloat16(v.y);
    o[2] = __float2bfloat16(v.z); o[3] = __float2bfloat16(v.w);
  }
}

// b2w1[h'] = sum_d b2[d] * W1[d][h']   (W1 f32 [1024][2048])
__global__ void b2w1_kernel(const float* __restrict__ b2, const float* __restrict__ W1,
                            float* __restrict__ out) {
  const int h = blockIdx.x * 256 + threadIdx.x;
  float s = 0.f;
  for (int d = 0; d < Ddim; ++d) s += b2[d] * W1[(size_t)d * Hdim + h];
  out[h] = s;
}

extern "C" void kernel_launch(void* const* d_in, const int* in_sizes, int n_in, void* d_out,
                              int out_size, void* d_ws, size_t ws_size, hipStream_t stream) {
  const float* x = (const float*)d_in[0];
  const float* W1 = (const float*)d_in[1];
  const float* b1 = (const float*)d_in[2];
  const float* W2 = (const float*)d_in[3];
  const float* b2 = (const float*)d_in[4];
  float* y = (float*)d_out;

  char* ws = (char*)d_ws;
  bf16* W1t = (bf16*)(ws + 0);                  // [2048][1024] bf16, 4 MB   (W1^T)
  bf16* W2bf = (bf16*)(ws + (4ull << 20));      // [2048][1024] bf16, 4 MB   (W2 rm)
  bf16* W2t = (bf16*)(ws + (8ull << 20));       // [1024][2048] bf16, 4 MB   (W2^T)
  bf16* W21t = (bf16*)(ws + (12ull << 20));     // [2048][2048] bf16, 8 MB   ((W2@W1)^T)
  bf16* xbf = (bf16*)(ws + (20ull << 20));      // [512][1024] bf16, 1 MB
  bf16* Tbuf = (bf16*)(ws + (21ull << 20));     // [512][2048] bf16, 2 MB
  bf16* Kbuf = (bf16*)(ws + (23ull << 20));     // 5 x MH bf16 (owner layout), 10 MB
  bf16* Gbf = (bf16*)(ws + (33ull << 20));      // [512][2048] bf16, 2 MB (row-major)
  float* yW1 = (float*)(ws + (35ull << 20));    // MH f32 (owner layout), 4 MB
  unsigned short* Gown = (unsigned short*)(ws + (39ull << 20));  // MH bf16 owner, 2 MB
  float* b2w1 = (float*)(ws + (43ull << 20));   // [2048] f32

  GArgs a = {};
  a.b1 = b1; a.b2w1 = b2w1; a.xin = x; a.b2 = b2;
  a.yW1 = yW1; a.T = Tbuf; a.K = Kbuf; a.G = Gown; a.y = y;

  constexpr int SMEM = 131072;
  hipFuncSetAttribute((const void*)&fused_gemm<M_PLAIN, 0, Hdim, 1024>,
                      hipFuncAttributeMaxDynamicSharedMemorySize, SMEM);
  hipFuncSetAttribute((const void*)&fused_gemm<M_INIT, 0, Hdim, 1024>,
                      hipFuncAttributeMaxDynamicSharedMemorySize, SMEM);
  hipFuncSetAttribute((const void*)&fused_gemm<M_STG, 1, Hdim, Hdim>,
                      hipFuncAttributeMaxDynamicSharedMemorySize, SMEM);
  hipFuncSetAttribute((const void*)&fused_gemm<M_STG, 2, Hdim, Hdim>,
                      hipFuncAttributeMaxDynamicSharedMemorySize, SMEM);
  hipFuncSetAttribute((const void*)&fused_gemm<M_STG, 3, Hdim, Hdim>,
                      hipFuncAttributeMaxDynamicSharedMemorySize, SMEM);
  hipFuncSetAttribute((const void*)&fused_gemm<M_STG, 4, Hdim, Hdim>,
                      hipFuncAttributeMaxDynamicSharedMemorySize, SMEM);
  hipFuncSetAttribute((const void*)&fused_gemm<M_STG, 5, Hdim, Hdim>,
                      hipFuncAttributeMaxDynamicSharedMemorySize, SMEM);
  hipFuncSetAttribute((const void*)&fused_gemm<M_STG, 6, Hdim, Hdim>,
                      hipFuncAttributeMaxDynamicSharedMemorySize, SMEM);
  hipFuncSetAttribute((const void*)&fused_gemm<M_FINAL, 0, Ddim, Hdim>,
                      hipFuncAttributeMaxDynamicSharedMemorySize, SMEM);

  // ---- setup (one-time) ----
  transpose_to_bf16<<<dim3(Hdim / 32, Ddim / 32), dim3(32, 8), 0, stream>>>(W1, W1t, Ddim, Hdim);
  transpose_to_bf16<<<dim3(Ddim / 32, Hdim / 32), dim3(32, 8), 0, stream>>>(W2, W2t, Hdim, Ddim);
  cast_bf16<<<(Hdim * Ddim / 4 + 255) / 256, 256, 0, stream>>>(W2, W2bf, Hdim * Ddim / 4);
  cast_bf16<<<(Mdim * Ddim / 4 + 255) / 256, 256, 0, stream>>>(x, xbf, Mdim * Ddim / 4);
  b2w1_kernel<<<Hdim / 256, 256, 0, stream>>>(b2, W1, b2w1);

  // W21t[h'][h] = sum_d W1[d,h']*W2[h,d]  : A=W1t [2048][1024], Bt=W2bf [2048][1024]
  {
    GArgs p = a; p.A = W1t; p.Bt = W2bf; p.Wout = W21t;
    fused_gemm<M_PLAIN, 0, Hdim, 1024><<<32 * 32, 512, SMEM, stream>>>(p);
  }
  // init: yW1 = x@W1 (owner layout) ; T1 = tanh(+b1) ; G = CF5[0]*tanh (owner bf16)
  {
    GArgs p = a; p.A = xbf; p.Bt = W1t;
    fused_gemm<M_INIT, 0, Hdim, 1024><<<8 * 32, 512, SMEM, stream>>>(p);
  }

  // ---- 16 RK steps, one H-space GEMM per stage (skip last step's stage 6) ----
  GArgs sg = a; sg.A = Tbuf; sg.Bt = W21t;
  for (int step = 0; step < 16; ++step) {
    fused_gemm<M_STG, 1, Hdim, Hdim><<<8 * 32, 512, SMEM, stream>>>(sg);
    fused_gemm<M_STG, 2, Hdim, Hdim><<<8 * 32, 512, SMEM, stream>>>(sg);
    fused_gemm<M_STG, 3, Hdim, Hdim><<<8 * 32, 512, SMEM, stream>>>(sg);
    fused_gemm<M_STG, 4, Hdim, Hdim><<<8 * 32, 512, SMEM, stream>>>(sg);
    fused_gemm<M_STG, 5, Hdim, Hdim><<<8 * 32, 512, SMEM, stream>>>(sg);
    if (step < 15)
      fused_gemm<M_STG, 6, Hdim, Hdim><<<8 * 32, 512, SMEM, stream>>>(sg);
  }

  // ---- final: y = x + Gbf@W2 + b2 ----
  gcvt<<<Mdim * (Hdim / 8) / 256, 256, 0, stream>>>(Gown, Gbf);
  {
    GArgs p = a; p.A = Gbf; p.Bt = W2t;
    fused_gemm<M_FINAL, 0, Ddim, Hdim><<<8 * 16, 512, SMEM, stream>>>(p);
  }
}

// Round 16
// 1208.554 us; speedup vs baseline: 1.2318x; 1.0530x over previous
//
#include <hip/hip_runtime.h>
#include <hip/hip_bf16.h>

using bf16 = __hip_bfloat16;
typedef __attribute__((ext_vector_type(8))) short short8;   // 8 bf16 (MFMA A/B frag)
typedef __attribute__((ext_vector_type(4))) float f32x4;
typedef __attribute__((ext_vector_type(16))) float f32x16;  // 32x32 MFMA C/D
typedef __attribute__((ext_vector_type(4))) unsigned short u16x4;  // 4 bf16 chunk

#define MFMA32(A, B, C) __builtin_amdgcn_mfma_f32_32x32x16_bf16(A, B, C, 0, 0, 0)

constexpr int Mdim = 512;
constexpr int Ddim = 1024;
constexpr int Hdim = 2048;
constexpr size_t MH = (size_t)Mdim * Hdim;   // 512*2048 (H-space activations)
constexpr size_t KPL4 = MH / 4;              // owner-layout chunks per plane

constexpr double Hs = 1.0 / 16.0;
// CF[s-1][j]: coefficient (times h) of K_{j+1} in the combination after stage s.
// Row 5 = 5th-order solution weights (also the G-accumulation weights).
constexpr float CF[6][6] = {
    {float(Hs * 1 / 5.), 0.f, 0.f, 0.f, 0.f, 0.f},
    {float(Hs * 3 / 40.), float(Hs * 9 / 40.), 0.f, 0.f, 0.f, 0.f},
    {float(Hs * 44 / 45.), float(-Hs * 56 / 15.), float(Hs * 32 / 9.), 0.f, 0.f, 0.f},
    {float(Hs * 19372 / 6561.), float(-Hs * 25360 / 2187.), float(Hs * 64448 / 6561.),
     float(-Hs * 212 / 729.), 0.f, 0.f},
    {float(Hs * 9017 / 3168.), float(-Hs * 355 / 33.), float(Hs * 46732 / 5247.),
     float(Hs * 49 / 176.), float(-Hs * 5103 / 18656.), 0.f},
    {float(Hs * 35 / 384.), 0.f, float(Hs * 500 / 1113.), float(Hs * 125 / 192.),
     float(-Hs * 2187 / 6784.), float(Hs * 11 / 84.)},
};

__device__ __forceinline__ float tanh_fast(float x) {
  float xc = fminf(fmaxf(x, -15.0f), 15.0f);
  float t = __expf(2.0f * xc);
  return (t - 1.0f) * __builtin_amdgcn_rcpf(t + 1.0f);
}

__device__ __forceinline__ unsigned short f2bf(float x) {
  bf16 b = __float2bfloat16(x);
  return *(unsigned short*)&b;
}
__device__ __forceinline__ float bf2f(unsigned short u) {
  bf16 b = *(bf16*)&u;
  return __bfloat162float(b);
}

__device__ __forceinline__ void gload_lds16(const void* g, void* lds) {
  __builtin_amdgcn_global_load_lds((const __attribute__((address_space(1))) void*)g,
                                   (__attribute__((address_space(3))) void*)lds, 16, 0, 0);
}

enum { M_PLAIN = 0, M_INIT = 1, M_STG = 2, M_FINAL = 3 };

struct GArgs {
  const bf16* A;      // [M][KDIM] bf16 row-major
  const bf16* Bt;     // [NDIM][KDIM] bf16 row-major (B transposed)
  const float* b1;    // bias for tanh input [NDIM]
  const float* b2w1;  // b2@W1 [2048]
  const float* xin;   // x f32 (FINAL)
  const float* b2;    // b2 (FINAL)
  float* yW1;         // MH f32, OWNER layout (f32x4 per (tile,q,lane))
  bf16* T;            // [512][2048] bf16 tanh output, row-major (next GEMM's A)
  bf16* K;            // 5 x MH bf16 K_j storage, OWNER layout (u16x4 chunks)
  unsigned short* G;  // MH bf16 accumulated CF5-weighted tanh, OWNER layout
  bf16* Wout;         // PLAIN bf16 output (W21t)
  float* y;           // FINAL f32 output
};

// C = A(M x KDIM) * Bt^T; 64x64 block tile; 8 waves, EACH with the full 64x64 tile
// (2x2 frags of mfma_32x32x16_bf16) on a disjoint K=16 slice => every staged LDS
// byte is ds_read exactly ONCE. BK=128, FOUR 32KB buffers, prefetch distance 3,
// counted vmcnt(8): {vmcnt(8); s_barrier; sched_barrier; stage(t+3); read+MFMA(t)}
// -- each tile's loads get ~3 iterations to land (absorbs peer-XCD T-read
// latency); no full drain until the final 2 iters. Buffer overwritten at iter t
// is tile t-1's, whose reads completed before this iter's barrier. No setprio
// (T5 is null on barrier-lockstep structures, m190). 8-way K-reduce via 128KB
// LDS exchange; owner (wid*2+of) sums 8 and runs the epilogue on all 512 threads.
// Owner layouts: yW1/K/G internal scratch -> (tile,q,lane) f32x4/u16x4 chunks,
// coalesced single-instruction access; G bf16 (halves largest epilogue RMW).
// 32x32 C/D layout (m74/m101): col=lane&31, row=(g*8)+(hi*4)+e with q=(frag<<2)|g.
// XOR swizzle (involution on 16B chunks, source-side) for ds_read bank spread.
// Grid XCD-swizzled: NP n-tiles per XCD share a weight slice (L2-resident).
template <int MODE, int STAGE, int NDIM, int KDIM>
__global__ __launch_bounds__(512, 2) void fused_gemm(GArgs a) {
  constexpr int BK = 128;
  constexpr int NITER = KDIM / BK;
  constexpr int NP = (NDIM / 64) / 8;

  extern __shared__ char smem_c[];  // 131072: staging 4x32KB; exchange 128KB aliased

  const int tid = threadIdx.x;
  const int lane = tid & 63;
  const int wid = tid >> 6;          // K-slice id (K=16 within BK=128)
  const int l31 = lane & 31;
  const int hi = lane >> 5;

  const int bid = blockIdx.x;
  const int nt = (bid & 7) * NP + ((bid >> 3) % NP);
  const int mt = (bid >> 3) / NP;
  const int brow = mt * 64, bcol = nt * 64;
  const int tile = mt * (NDIM / 64) + nt;   // stable across all dispatches

  // ---- staging: per matrix 64 rows x 16 chunks(16B) = 1024 chunks; thread covers
  // q = tid (rows 0..31) and q = tid+512 (rows 32..63) at fixed swizzled source
  // chunk (cs^(r&7); r&7 invariant under +32). LDS dest linear (gload constraint).
  const int rs0 = tid >> 4;
  const int cgS = (tid & 15) ^ (rs0 & 7);
  const bf16* pA0 = a.A + (size_t)(brow + rs0) * KDIM + cgS * 8;
  const bf16* pA1 = pA0 + (size_t)32 * KDIM;
  const bf16* pB0 = a.Bt + (size_t)(bcol + rs0) * KDIM + cgS * 8;
  const bf16* pB1 = pB0 + (size_t)32 * KDIM;
  char* dA = smem_c + tid * 16;            // A region [0,16K) of each buffer
  char* dB = smem_c + 16384 + tid * 16;    // B region [16K,32K)

#define STAGE_TILE(T_)                                                       \
  {                                                                          \
    const int B_ = ((T_) % 4) * 32768;                                       \
    const int KO_ = (T_)*BK;                                                 \
    gload_lds16(pA0 + KO_, dA + B_); gload_lds16(pA1 + KO_, dA + B_ + 8192); \
    gload_lds16(pB0 + KO_, dB + B_); gload_lds16(pB1 + KO_, dB + B_ + 8192); \
  }

  // ---- ds_read per-lane offset: row = l31, chunk = (wid*2 + hi) ^ (row&7).
  const int xo = l31 * 256 + (((wid * 2 + hi) ^ (l31 & 7)) << 4);
  const char* rA = smem_c + xo;              // + mf*8192 + buf
  const char* rB = smem_c + 16384 + xo;      // + nf*8192 + buf

  f32x16 acc[2][2] = {};   // [mf][nf] 32x32 frags, this wave's K-slice partial

  STAGE_TILE(0)
  STAGE_TILE(1)
  STAGE_TILE(2)

#pragma unroll
  for (int t = 0; t < NITER; ++t) {
    // distance-3 counted waits: tile t's 4 loads are the oldest; 8 newer (t+1,t+2)
    // may stay in flight. Tail drains 8 -> 4 -> 0.
    if (t < NITER - 2)       asm volatile("s_waitcnt vmcnt(8)" ::: "memory");
    else if (t == NITER - 2) asm volatile("s_waitcnt vmcnt(4)" ::: "memory");
    else                     asm volatile("s_waitcnt vmcnt(0)" ::: "memory");
    __builtin_amdgcn_s_barrier();
    __builtin_amdgcn_sched_barrier(0);
    if (t + 3 < NITER) STAGE_TILE(t + 3)
    const int BO = (t % 4) * 32768;
    short8 af0 = *(const short8*)(rA + BO);
    short8 af1 = *(const short8*)(rA + BO + 8192);
    short8 bw0 = *(const short8*)(rB + BO);
    short8 bw1 = *(const short8*)(rB + BO + 8192);
    acc[0][0] = MFMA32(af0, bw0, acc[0][0]);
    acc[0][1] = MFMA32(af0, bw1, acc[0][1]);
    acc[1][0] = MFMA32(af1, bw0, acc[1][0]);
    acc[1][1] = MFMA32(af1, bw1, acc[1][1]);
  }
#undef STAGE_TILE

  // ---- 8-way K-reduce via owner distribution: chunk q = (mf*2+nf)*4 + g ----
  __syncthreads();
#pragma unroll
  for (int mf = 0; mf < 2; ++mf)
#pragma unroll
    for (int nf = 0; nf < 2; ++nf)
#pragma unroll
      for (int g = 0; g < 4; ++g) {
        f32x4 v = {acc[mf][nf][g * 4 + 0], acc[mf][nf][g * 4 + 1],
                   acc[mf][nf][g * 4 + 2], acc[mf][nf][g * 4 + 3]};
        *(f32x4*)(smem_c + ((((mf * 2 + nf) * 4 + g) * 8 + wid) << 10) + lane * 16) = v;
      }
  __syncthreads();

#pragma unroll
  for (int of = 0; of < 2; ++of) {
    const int q = wid * 2 + of;        // owned chunk 0..15
    f32x4 s = {};
#pragma unroll
    for (int w = 0; w < 8; ++w)
      s += *(const f32x4*)(smem_c + (((q * 8 + w) << 10)) + lane * 16);

    // Epilogue (all 512 threads). q -> frag p=q>>2 (mf=p>>1, nf=p&1), reg-group g=q&3.
    const int p = q >> 2, g = q & 3;
    const int mf = p >> 1, nf = p & 1;
    const int c = bcol + nf * 32 + l31;
    const int r0 = brow + mf * 32 + g * 8 + hi * 4;   // rows r0..r0+3
    const size_t kb = (size_t)(tile * 16 + q) * 64 + lane;  // owner chunk index
    if constexpr (MODE == M_PLAIN) {
#pragma unroll
      for (int e = 0; e < 4; ++e) a.Wout[(size_t)(r0 + e) * NDIM + c] = __float2bfloat16(s[e]);
    } else if constexpr (MODE == M_INIT) {
      ((f32x4*)a.yW1)[kb] = s;
      const float bv = a.b1[c];
      float tv[4];
#pragma unroll
      for (int e = 0; e < 4; ++e) {
        tv[e] = tanh_fast(s[e] + bv);
        a.T[(size_t)(r0 + e) * NDIM + c] = __float2bfloat16(tv[e]);
      }
      u16x4 gw;
#pragma unroll
      for (int e = 0; e < 4; ++e) gw[e] = f2bf(CF[5][0] * tv[e]);
      ((u16x4*)a.G)[kb] = gw;
    } else if constexpr (MODE == M_STG) {
      u16x4* Kq = (u16x4*)a.K;
      const float bb = a.b2w1[c];
      float Kv[4], comb[4];
      const f32x4 yv = ((const f32x4*)a.yW1)[kb];
#pragma unroll
      for (int e = 0; e < 4; ++e) Kv[e] = s[e] + bb;
      if constexpr (STAGE <= 5) {
        u16x4 kw;
#pragma unroll
        for (int e = 0; e < 4; ++e) kw[e] = f2bf(Kv[e]);
        Kq[(size_t)(STAGE - 1) * KPL4 + kb] = kw;     // coalesced 8B/lane
      }
#pragma unroll
      for (int e = 0; e < 4; ++e) comb[e] = yv[e] + CF[STAGE - 1][STAGE - 1] * Kv[e];
      if constexpr (STAGE > 1 && CF[STAGE - 1][0] != 0.f) {
        u16x4 kj = Kq[0 * KPL4 + kb];
#pragma unroll
        for (int e = 0; e < 4; ++e) comb[e] += CF[STAGE - 1][0] * bf2f(kj[e]);
      }
      if constexpr (STAGE > 2 && CF[STAGE - 1][1] != 0.f) {
        u16x4 kj = Kq[1 * KPL4 + kb];
#pragma unroll
        for (int e = 0; e < 4; ++e) comb[e] += CF[STAGE - 1][1] * bf2f(kj[e]);
      }
      if constexpr (STAGE > 3 && CF[STAGE - 1][2] != 0.f) {
        u16x4 kj = Kq[2 * KPL4 + kb];
#pragma unroll
        for (int e = 0; e < 4; ++e) comb[e] += CF[STAGE - 1][2] * bf2f(kj[e]);
      }
      if constexpr (STAGE > 4 && CF[STAGE - 1][3] != 0.f) {
        u16x4 kj = Kq[3 * KPL4 + kb];
#pragma unroll
        for (int e = 0; e < 4; ++e) comb[e] += CF[STAGE - 1][3] * bf2f(kj[e]);
      }
      if constexpr (STAGE > 5 && CF[STAGE - 1][4] != 0.f) {
        u16x4 kj = Kq[4 * KPL4 + kb];
#pragma unroll
        for (int e = 0; e < 4; ++e) comb[e] += CF[STAGE - 1][4] * bf2f(kj[e]);
      }
      if constexpr (STAGE == 6) {
        f32x4 cw = {comb[0], comb[1], comb[2], comb[3]};
        ((f32x4*)a.yW1)[kb] = cw;                     // 5th-order yW1 update
      }
      const float bv = a.b1[c];
      float tv[4];
#pragma unroll
      for (int e = 0; e < 4; ++e) {
        tv[e] = tanh_fast(comb[e] + bv);
        a.T[(size_t)(r0 + e) * NDIM + c] = __float2bfloat16(tv[e]);
      }
      constexpr float GW = (STAGE < 6) ? CF[5][STAGE] : CF[5][0];
      if constexpr (GW != 0.f) {
        u16x4 gv = ((const u16x4*)a.G)[kb];           // coalesced bf16 RMW
#pragma unroll
        for (int e = 0; e < 4; ++e) gv[e] = f2bf(bf2f(gv[e]) + GW * tv[e]);
        ((u16x4*)a.G)[kb] = gv;
      }
    } else {  // M_FINAL
      const float bv = a.b2[c];
#pragma unroll
      for (int e = 0; e < 4; ++e) {
        const size_t idx = (size_t)(r0 + e) * NDIM + c;
        a.y[idx] = a.xin[idx] + s[e] + bv;
      }
    }
  }
}

// Owner-layout bf16 G -> row-major bf16 (for final GEMM's A staging). One thread
// per (row, 8-col group); writes 16B contiguous.
__global__ void gcvt(const unsigned short* __restrict__ Gown, bf16* __restrict__ out) {
  const int t = blockIdx.x * 256 + threadIdx.x;   // 512*256 = 131072 threads
  const int row = t >> 8;
  const int c0 = (t & 255) * 8;
  const int mt = row >> 6, rm = row & 63;
  const int mf = rm >> 5, g = (rm >> 3) & 3, hi = (rm >> 2) & 1, e = rm & 3;
  const int nt = c0 >> 6, cn = c0 & 63;
  const int nf = cn >> 5;
  const int q = (mf * 2 + nf) * 4 + g;
  const size_t base = ((size_t)((mt * 32 + nt) * 16 + q) * 64 + hi * 32 + (cn & 31)) * 4 + e;
  bf16 tmp[8];
#pragma unroll
  for (int j = 0; j < 8; ++j) {
    unsigned short u = Gown[base + j * 4];
    tmp[j] = *(bf16*)&u;
  }
  *(short8*)(out + (size_t)row * 2048 + c0) = *(short8*)tmp;
}

// fp32 [R][C] -> bf16 [C][R]
__global__ void transpose_to_bf16(const float* __restrict__ in, bf16* __restrict__ out, int R,
                                  int C) {
  __shared__ float t[32][33];
  const int c0 = blockIdx.x * 32, r0 = blockIdx.y * 32;
#pragma unroll
  for (int i = threadIdx.y; i < 32; i += 8)
    t[i][threadIdx.x] = in[(size_t)(r0 + i) * C + c0 + threadIdx.x];
  __syncthreads();
#pragma unroll
  for (int i = threadIdx.y; i < 32; i += 8)
    out[(size_t)(c0 + i) * R + r0 + threadIdx.x] = __float2bfloat16(t[threadIdx.x][i]);
}

// fp32 -> bf16 elementwise (4 per thread)
__global__ void cast_bf16(const float* __restrict__ in, bf16* __restrict__ out, int n4) {
  int i = blockIdx.x * 256 + threadIdx.x;
  if (i < n4) {
    float4 v = *(const float4*)(in + i * 4);
    bf16* o = out + i * 4;
    o[0] = __float2bfloat16(v.x); o[1] = __float2bfloat16(v.y);
    o[2] = __float2bfloat16(v.z); o[3] = __float2bfloat16(v.w);
  }
}

// b2w1[h'] = sum_d b2[d] * W1[d][h']. Parallel over d: block = 16 h x 16 d-slices,
// grid 128 blocks (2048/16); LDS reduce over the 16 d-slices.
__global__ void b2w1_kernel(const float* __restrict__ b2, const float* __restrict__ W1,
                            float* __restrict__ out) {
  __shared__ float red[16][17];
  const int hl = threadIdx.x & 15;    // h within group
  const int ds = threadIdx.x >> 4;    // d-slice
  const int h = blockIdx.x * 16 + hl;
  float s = 0.f;
  for (int d = ds * 64; d < ds * 64 + 64; ++d) s += b2[d] * W1[(size_t)d * Hdim + h];
  red[ds][hl] = s;
  __syncthreads();
  if (ds == 0) {
    float t = 0.f;
#pragma unroll
    for (int k = 0; k < 16; ++k) t += red[k][hl];
    out[h] = t;
  }
}

extern "C" void kernel_launch(void* const* d_in, const int* in_sizes, int n_in, void* d_out,
                              int out_size, void* d_ws, size_t ws_size, hipStream_t stream) {
  const float* x = (const float*)d_in[0];
  const float* W1 = (const float*)d_in[1];
  const float* b1 = (const float*)d_in[2];
  const float* W2 = (const float*)d_in[3];
  const float* b2 = (const float*)d_in[4];
  float* y = (float*)d_out;

  char* ws = (char*)d_ws;
  bf16* W1t = (bf16*)(ws + 0);                  // [2048][1024] bf16, 4 MB   (W1^T)
  bf16* W2bf = (bf16*)(ws + (4ull << 20));      // [2048][1024] bf16, 4 MB   (W2 rm)
  bf16* W2t = (bf16*)(ws + (8ull << 20));       // [1024][2048] bf16, 4 MB   (W2^T)
  bf16* W21t = (bf16*)(ws + (12ull << 20));     // [2048][2048] bf16, 8 MB   ((W2@W1)^T)
  bf16* xbf = (bf16*)(ws + (20ull << 20));      // [512][1024] bf16, 1 MB
  bf16* Tbuf = (bf16*)(ws + (21ull << 20));     // [512][2048] bf16, 2 MB
  bf16* Kbuf = (bf16*)(ws + (23ull << 20));     // 5 x MH bf16 (owner layout), 10 MB
  bf16* Gbf = (bf16*)(ws + (33ull << 20));      // [512][2048] bf16, 2 MB (row-major)
  float* yW1 = (float*)(ws + (35ull << 20));    // MH f32 (owner layout), 4 MB
  unsigned short* Gown = (unsigned short*)(ws + (39ull << 20));  // MH bf16 owner, 2 MB
  float* b2w1 = (float*)(ws + (43ull << 20));   // [2048] f32

  GArgs a = {};
  a.b1 = b1; a.b2w1 = b2w1; a.xin = x; a.b2 = b2;
  a.yW1 = yW1; a.T = Tbuf; a.K = Kbuf; a.G = Gown; a.y = y;

  constexpr int SMEM = 131072;
  hipFuncSetAttribute((const void*)&fused_gemm<M_PLAIN, 0, Hdim, 1024>,
                      hipFuncAttributeMaxDynamicSharedMemorySize, SMEM);
  hipFuncSetAttribute((const void*)&fused_gemm<M_INIT, 0, Hdim, 1024>,
                      hipFuncAttributeMaxDynamicSharedMemorySize, SMEM);
  hipFuncSetAttribute((const void*)&fused_gemm<M_STG, 1, Hdim, Hdim>,
                      hipFuncAttributeMaxDynamicSharedMemorySize, SMEM);
  hipFuncSetAttribute((const void*)&fused_gemm<M_STG, 2, Hdim, Hdim>,
                      hipFuncAttributeMaxDynamicSharedMemorySize, SMEM);
  hipFuncSetAttribute((const void*)&fused_gemm<M_STG, 3, Hdim, Hdim>,
                      hipFuncAttributeMaxDynamicSharedMemorySize, SMEM);
  hipFuncSetAttribute((const void*)&fused_gemm<M_STG, 4, Hdim, Hdim>,
                      hipFuncAttributeMaxDynamicSharedMemorySize, SMEM);
  hipFuncSetAttribute((const void*)&fused_gemm<M_STG, 5, Hdim, Hdim>,
                      hipFuncAttributeMaxDynamicSharedMemorySize, SMEM);
  hipFuncSetAttribute((const void*)&fused_gemm<M_STG, 6, Hdim, Hdim>,
                      hipFuncAttributeMaxDynamicSharedMemorySize, SMEM);
  hipFuncSetAttribute((const void*)&fused_gemm<M_FINAL, 0, Ddim, Hdim>,
                      hipFuncAttributeMaxDynamicSharedMemorySize, SMEM);

  // ---- setup (one-time) ----
  transpose_to_bf16<<<dim3(Hdim / 32, Ddim / 32), dim3(32, 8), 0, stream>>>(W1, W1t, Ddim, Hdim);
  transpose_to_bf16<<<dim3(Ddim / 32, Hdim / 32), dim3(32, 8), 0, stream>>>(W2, W2t, Hdim, Ddim);
  cast_bf16<<<(Hdim * Ddim / 4 + 255) / 256, 256, 0, stream>>>(W2, W2bf, Hdim * Ddim / 4);
  cast_bf16<<<(Mdim * Ddim / 4 + 255) / 256, 256, 0, stream>>>(x, xbf, Mdim * Ddim / 4);
  b2w1_kernel<<<Hdim / 16, 256, 0, stream>>>(b2, W1, b2w1);

  // W21t[h'][h] = sum_d W1[d,h']*W2[h,d]  : A=W1t [2048][1024], Bt=W2bf [2048][1024]
  {
    GArgs p = a; p.A = W1t; p.Bt = W2bf; p.Wout = W21t;
    fused_gemm<M_PLAIN, 0, Hdim, 1024><<<32 * 32, 512, SMEM, stream>>>(p);
  }
  // init: yW1 = x@W1 (owner layout) ; T1 = tanh(+b1) ; G = CF5[0]*tanh (owner bf16)
  {
    GArgs p = a; p.A = xbf; p.Bt = W1t;
    fused_gemm<M_INIT, 0, Hdim, 1024><<<8 * 32, 512, SMEM, stream>>>(p);
  }

  // ---- 16 RK steps, one H-space GEMM per stage (skip last step's stage 6) ----
  GArgs sg = a; sg.A = Tbuf; sg.Bt = W21t;
  for (int step = 0; step < 16; ++step) {
    fused_gemm<M_STG, 1, Hdim, Hdim><<<8 * 32, 512, SMEM, stream>>>(sg);
    fused_gemm<M_STG, 2, Hdim, Hdim><<<8 * 32, 512, SMEM, stream>>>(sg);
    fused_gemm<M_STG, 3, Hdim, Hdim><<<8 * 32, 512, SMEM, stream>>>(sg);
    fused_gemm<M_STG, 4, Hdim, Hdim><<<8 * 32, 512, SMEM, stream>>>(sg);
    fused_gemm<M_STG, 5, Hdim, Hdim><<<8 * 32, 512, SMEM, stream>>>(sg);
    if (step < 15)
      fused_gemm<M_STG, 6, Hdim, Hdim><<<8 * 32, 512, SMEM, stream>>>(sg);
  }

  // ---- final: y = x + Gbf@W2 + b2 ----
  gcvt<<<Mdim * (Hdim / 8) / 256, 256, 0, stream>>>(Gown, Gbf);
  {
    GArgs p = a; p.A = Gbf; p.Bt = W2t;
    fused_gemm<M_FINAL, 0, Ddim, Hdim><<<8 * 16, 512, SMEM, stream>>>(p);
  }
}

// Round 17
// 1208.252 us; speedup vs baseline: 1.2321x; 1.0003x over previous
//
#include <hip/hip_runtime.h>
#include <hip/hip_bf16.h>

using bf16 = __hip_bfloat16;
typedef __attribute__((ext_vector_type(8))) short short8;   // 8 bf16 (MFMA A/B frag)
typedef __attribute__((ext_vector_type(4))) float f32x4;
typedef __attribute__((ext_vector_type(16))) float f32x16;  // 32x32 MFMA C/D
typedef __attribute__((ext_vector_type(4))) unsigned short u16x4;  // 4 bf16 chunk

#define MFMA32(A, B, C) __builtin_amdgcn_mfma_f32_32x32x16_bf16(A, B, C, 0, 0, 0)

constexpr int Mdim = 512;
constexpr int Ddim = 1024;
constexpr int Hdim = 2048;
constexpr size_t MH = (size_t)Mdim * Hdim;   // 512*2048 (H-space activations)
constexpr size_t KPL4 = MH / 4;              // owner-layout chunks per plane

constexpr double Hs = 1.0 / 16.0;
// CF[s-1][j]: coefficient (times h) of K_{j+1} in the combination after stage s.
// Row 5 = 5th-order solution weights (also the G-accumulation weights).
constexpr float CF[6][6] = {
    {float(Hs * 1 / 5.), 0.f, 0.f, 0.f, 0.f, 0.f},
    {float(Hs * 3 / 40.), float(Hs * 9 / 40.), 0.f, 0.f, 0.f, 0.f},
    {float(Hs * 44 / 45.), float(-Hs * 56 / 15.), float(Hs * 32 / 9.), 0.f, 0.f, 0.f},
    {float(Hs * 19372 / 6561.), float(-Hs * 25360 / 2187.), float(Hs * 64448 / 6561.),
     float(-Hs * 212 / 729.), 0.f, 0.f},
    {float(Hs * 9017 / 3168.), float(-Hs * 355 / 33.), float(Hs * 46732 / 5247.),
     float(Hs * 49 / 176.), float(-Hs * 5103 / 18656.), 0.f},
    {float(Hs * 35 / 384.), 0.f, float(Hs * 500 / 1113.), float(Hs * 125 / 192.),
     float(-Hs * 2187 / 6784.), float(Hs * 11 / 84.)},
};

__device__ __forceinline__ float tanh_fast(float x) {
  float xc = fminf(fmaxf(x, -15.0f), 15.0f);
  float t = __expf(2.0f * xc);
  return (t - 1.0f) * __builtin_amdgcn_rcpf(t + 1.0f);
}

__device__ __forceinline__ unsigned short f2bf(float x) {
  bf16 b = __float2bfloat16(x);
  return *(unsigned short*)&b;
}
__device__ __forceinline__ float bf2f(unsigned short u) {
  bf16 b = *(bf16*)&u;
  return __bfloat162float(b);
}

__device__ __forceinline__ void gload_lds16(const void* g, void* lds) {
  __builtin_amdgcn_global_load_lds((const __attribute__((address_space(1))) void*)g,
                                   (__attribute__((address_space(3))) void*)lds, 16, 0, 0);
}

enum { M_PLAIN = 0, M_INIT = 1, M_STG = 2, M_FINAL = 3 };

struct GArgs {
  const bf16* A;      // [M][KDIM] bf16 row-major
  const bf16* Bt;     // [NDIM][KDIM] bf16 row-major (B transposed)
  const float* b1;    // bias for tanh input [NDIM]
  const float* b2w1;  // b2@W1 [2048]
  const float* xin;   // x f32 (FINAL)
  const float* b2;    // b2 (FINAL)
  float* yW1;         // MH f32, OWNER layout (f32x4 per (tile,q,lane))
  bf16* T;            // [512][2048] bf16 tanh output, row-major (next GEMM's A)
  bf16* K;            // 5 x MH bf16 K_j storage, OWNER layout (u16x4 chunks)
  unsigned short* G;  // MH bf16 accumulated CF5-weighted tanh, OWNER layout
  bf16* Wout;         // PLAIN bf16 output (W21t)
  float* y;           // FINAL f32 output
};

// C = A(M x KDIM) * Bt^T; 64x64 block tile; 8 waves, EACH with the full 64x64 tile
// (2x2 frags of mfma_32x32x16_bf16) on a disjoint K=16 slice => every staged LDS
// byte is ds_read exactly ONCE. BK=128, FOUR 32KB buffers, prefetch distance 3,
// counted vmcnt(8): {vmcnt(8); s_barrier; sched_barrier; stage(t+3); read+MFMA(t)}
// -- each tile's loads get ~3 iterations to land (absorbs peer-XCD T-read
// latency); no full drain until the final 2 iters. Buffer overwritten at iter t
// is tile t-1's, whose reads completed before this iter's barrier.
// __launch_bounds__(512) WITHOUT a min-waves arg: 131072B LDS already limits to
// 1 block/CU, so the old ",2" only capped VGPRs at 128 (spilling the epilogue);
// uncapped lets the allocator keep acc(64) + operands + epilogue temps resident.
// 8-way K-reduce via 128KB LDS exchange; owner (wid*2+of) sums 8 and runs the
// epilogue on all 512 threads. Owner layouts: yW1/K/G internal scratch ->
// (tile,q,lane) f32x4/u16x4 chunks, coalesced; G bf16 (halves largest RMW).
// 32x32 C/D layout (m74/m101): col=lane&31, row=(g*8)+(hi*4)+e with q=(frag<<2)|g.
// XOR swizzle (involution on 16B chunks, source-side) for ds_read bank spread.
// Grid XCD-swizzled: NP n-tiles per XCD share a weight slice (L2-resident).
template <int MODE, int STAGE, int NDIM, int KDIM>
__global__ __launch_bounds__(512) void fused_gemm(GArgs a) {
  constexpr int BK = 128;
  constexpr int NITER = KDIM / BK;
  constexpr int NP = (NDIM / 64) / 8;

  extern __shared__ char smem_c[];  // 131072: staging 4x32KB; exchange 128KB aliased

  const int tid = threadIdx.x;
  const int lane = tid & 63;
  const int wid = tid >> 6;          // K-slice id (K=16 within BK=128)
  const int l31 = lane & 31;
  const int hi = lane >> 5;

  const int bid = blockIdx.x;
  const int nt = (bid & 7) * NP + ((bid >> 3) % NP);
  const int mt = (bid >> 3) / NP;
  const int brow = mt * 64, bcol = nt * 64;
  const int tile = mt * (NDIM / 64) + nt;   // stable across all dispatches

  // ---- staging: per matrix 64 rows x 16 chunks(16B) = 1024 chunks; thread covers
  // q = tid (rows 0..31) and q = tid+512 (rows 32..63) at fixed swizzled source
  // chunk (cs^(r&7); r&7 invariant under +32). LDS dest linear (gload constraint).
  const int rs0 = tid >> 4;
  const int cgS = (tid & 15) ^ (rs0 & 7);
  const bf16* pA0 = a.A + (size_t)(brow + rs0) * KDIM + cgS * 8;
  const bf16* pA1 = pA0 + (size_t)32 * KDIM;
  const bf16* pB0 = a.Bt + (size_t)(bcol + rs0) * KDIM + cgS * 8;
  const bf16* pB1 = pB0 + (size_t)32 * KDIM;
  char* dA = smem_c + tid * 16;            // A region [0,16K) of each buffer
  char* dB = smem_c + 16384 + tid * 16;    // B region [16K,32K)

#define STAGE_TILE(T_)                                                       \
  {                                                                          \
    const int B_ = ((T_) % 4) * 32768;                                       \
    const int KO_ = (T_)*BK;                                                 \
    gload_lds16(pA0 + KO_, dA + B_); gload_lds16(pA1 + KO_, dA + B_ + 8192); \
    gload_lds16(pB0 + KO_, dB + B_); gload_lds16(pB1 + KO_, dB + B_ + 8192); \
  }

  // ---- ds_read per-lane offset: row = l31, chunk = (wid*2 + hi) ^ (row&7).
  const int xo = l31 * 256 + (((wid * 2 + hi) ^ (l31 & 7)) << 4);
  const char* rA = smem_c + xo;              // + mf*8192 + buf
  const char* rB = smem_c + 16384 + xo;      // + nf*8192 + buf

  f32x16 acc[2][2] = {};   // [mf][nf] 32x32 frags, this wave's K-slice partial

  STAGE_TILE(0)
  STAGE_TILE(1)
  STAGE_TILE(2)

#pragma unroll
  for (int t = 0; t < NITER; ++t) {
    // distance-3 counted waits: tile t's 4 loads are the oldest; 8 newer (t+1,t+2)
    // may stay in flight. Tail drains 8 -> 4 -> 0.
    if (t < NITER - 2)       asm volatile("s_waitcnt vmcnt(8)" ::: "memory");
    else if (t == NITER - 2) asm volatile("s_waitcnt vmcnt(4)" ::: "memory");
    else                     asm volatile("s_waitcnt vmcnt(0)" ::: "memory");
    __builtin_amdgcn_s_barrier();
    __builtin_amdgcn_sched_barrier(0);
    if (t + 3 < NITER) STAGE_TILE(t + 3)
    const int BO = (t % 4) * 32768;
    short8 af0 = *(const short8*)(rA + BO);
    short8 af1 = *(const short8*)(rA + BO + 8192);
    short8 bw0 = *(const short8*)(rB + BO);
    short8 bw1 = *(const short8*)(rB + BO + 8192);
    acc[0][0] = MFMA32(af0, bw0, acc[0][0]);
    acc[0][1] = MFMA32(af0, bw1, acc[0][1]);
    acc[1][0] = MFMA32(af1, bw0, acc[1][0]);
    acc[1][1] = MFMA32(af1, bw1, acc[1][1]);
  }
#undef STAGE_TILE

  // ---- 8-way K-reduce via owner distribution: chunk q = (mf*2+nf)*4 + g ----
  __syncthreads();
#pragma unroll
  for (int mf = 0; mf < 2; ++mf)
#pragma unroll
    for (int nf = 0; nf < 2; ++nf)
#pragma unroll
      for (int g = 0; g < 4; ++g) {
        f32x4 v = {acc[mf][nf][g * 4 + 0], acc[mf][nf][g * 4 + 1],
                   acc[mf][nf][g * 4 + 2], acc[mf][nf][g * 4 + 3]};
        *(f32x4*)(smem_c + ((((mf * 2 + nf) * 4 + g) * 8 + wid) << 10) + lane * 16) = v;
      }
  __syncthreads();

#pragma unroll
  for (int of = 0; of < 2; ++of) {
    const int q = wid * 2 + of;        // owned chunk 0..15
    f32x4 s = {};
#pragma unroll
    for (int w = 0; w < 8; ++w)
      s += *(const f32x4*)(smem_c + (((q * 8 + w) << 10)) + lane * 16);

    // Epilogue (all 512 threads). q -> frag p=q>>2 (mf=p>>1, nf=p&1), reg-group g=q&3.
    const int p = q >> 2, g = q & 3;
    const int mf = p >> 1, nf = p & 1;
    const int c = bcol + nf * 32 + l31;
    const int r0 = brow + mf * 32 + g * 8 + hi * 4;   // rows r0..r0+3
    const size_t kb = (size_t)(tile * 16 + q) * 64 + lane;  // owner chunk index
    if constexpr (MODE == M_PLAIN) {
#pragma unroll
      for (int e = 0; e < 4; ++e) a.Wout[(size_t)(r0 + e) * NDIM + c] = __float2bfloat16(s[e]);
    } else if constexpr (MODE == M_INIT) {
      ((f32x4*)a.yW1)[kb] = s;
      const float bv = a.b1[c];
      float tv[4];
#pragma unroll
      for (int e = 0; e < 4; ++e) {
        tv[e] = tanh_fast(s[e] + bv);
        a.T[(size_t)(r0 + e) * NDIM + c] = __float2bfloat16(tv[e]);
      }
      u16x4 gw;
#pragma unroll
      for (int e = 0; e < 4; ++e) gw[e] = f2bf(CF[5][0] * tv[e]);
      ((u16x4*)a.G)[kb] = gw;
    } else if constexpr (MODE == M_STG) {
      u16x4* Kq = (u16x4*)a.K;
      const float bb = a.b2w1[c];
      float Kv[4], comb[4];
      const f32x4 yv = ((const f32x4*)a.yW1)[kb];
#pragma unroll
      for (int e = 0; e < 4; ++e) Kv[e] = s[e] + bb;
      if constexpr (STAGE <= 5) {
        u16x4 kw;
#pragma unroll
        for (int e = 0; e < 4; ++e) kw[e] = f2bf(Kv[e]);
        Kq[(size_t)(STAGE - 1) * KPL4 + kb] = kw;     // coalesced 8B/lane
      }
#pragma unroll
      for (int e = 0; e < 4; ++e) comb[e] = yv[e] + CF[STAGE - 1][STAGE - 1] * Kv[e];
      if constexpr (STAGE > 1 && CF[STAGE - 1][0] != 0.f) {
        u16x4 kj = Kq[0 * KPL4 + kb];
#pragma unroll
        for (int e = 0; e < 4; ++e) comb[e] += CF[STAGE - 1][0] * bf2f(kj[e]);
      }
      if constexpr (STAGE > 2 && CF[STAGE - 1][1] != 0.f) {
        u16x4 kj = Kq[1 * KPL4 + kb];
#pragma unroll
        for (int e = 0; e < 4; ++e) comb[e] += CF[STAGE - 1][1] * bf2f(kj[e]);
      }
      if constexpr (STAGE > 3 && CF[STAGE - 1][2] != 0.f) {
        u16x4 kj = Kq[2 * KPL4 + kb];
#pragma unroll
        for (int e = 0; e < 4; ++e) comb[e] += CF[STAGE - 1][2] * bf2f(kj[e]);
      }
      if constexpr (STAGE > 4 && CF[STAGE - 1][3] != 0.f) {
        u16x4 kj = Kq[3 * KPL4 + kb];
#pragma unroll
        for (int e = 0; e < 4; ++e) comb[e] += CF[STAGE - 1][3] * bf2f(kj[e]);
      }
      if constexpr (STAGE > 5 && CF[STAGE - 1][4] != 0.f) {
        u16x4 kj = Kq[4 * KPL4 + kb];
#pragma unroll
        for (int e = 0; e < 4; ++e) comb[e] += CF[STAGE - 1][4] * bf2f(kj[e]);
      }
      if constexpr (STAGE == 6) {
        f32x4 cw = {comb[0], comb[1], comb[2], comb[3]};
        ((f32x4*)a.yW1)[kb] = cw;                     // 5th-order yW1 update
      }
      const float bv = a.b1[c];
      float tv[4];
#pragma unroll
      for (int e = 0; e < 4; ++e) {
        tv[e] = tanh_fast(comb[e] + bv);
        a.T[(size_t)(r0 + e) * NDIM + c] = __float2bfloat16(tv[e]);
      }
      constexpr float GW = (STAGE < 6) ? CF[5][STAGE] : CF[5][0];
      if constexpr (GW != 0.f) {
        u16x4 gv = ((const u16x4*)a.G)[kb];           // coalesced bf16 RMW
#pragma unroll
        for (int e = 0; e < 4; ++e) gv[e] = f2bf(bf2f(gv[e]) + GW * tv[e]);
        ((u16x4*)a.G)[kb] = gv;
      }
    } else {  // M_FINAL
      const float bv = a.b2[c];
#pragma unroll
      for (int e = 0; e < 4; ++e) {
        const size_t idx = (size_t)(r0 + e) * NDIM + c;
        a.y[idx] = a.xin[idx] + s[e] + bv;
      }
    }
  }
}

// Owner-layout bf16 G -> row-major bf16 (for final GEMM's A staging). One thread
// per (row, 8-col group); writes 16B contiguous.
__global__ void gcvt(const unsigned short* __restrict__ Gown, bf16* __restrict__ out) {
  const int t = blockIdx.x * 256 + threadIdx.x;   // 512*256 = 131072 threads
  const int row = t >> 8;
  const int c0 = (t & 255) * 8;
  const int mt = row >> 6, rm = row & 63;
  const int mf = rm >> 5, g = (rm >> 3) & 3, hi = (rm >> 2) & 1, e = rm & 3;
  const int nt = c0 >> 6, cn = c0 & 63;
  const int nf = cn >> 5;
  const int q = (mf * 2 + nf) * 4 + g;
  const size_t base = ((size_t)((mt * 32 + nt) * 16 + q) * 64 + hi * 32 + (cn & 31)) * 4 + e;
  bf16 tmp[8];
#pragma unroll
  for (int j = 0; j < 8; ++j) {
    unsigned short u = Gown[base + j * 4];
    tmp[j] = *(bf16*)&u;
  }
  *(short8*)(out + (size_t)row * 2048 + c0) = *(short8*)tmp;
}

// fp32 [R][C] -> bf16 [C][R]
__global__ void transpose_to_bf16(const float* __restrict__ in, bf16* __restrict__ out, int R,
                                  int C) {
  __shared__ float t[32][33];
  const int c0 = blockIdx.x * 32, r0 = blockIdx.y * 32;
#pragma unroll
  for (int i = threadIdx.y; i < 32; i += 8)
    t[i][threadIdx.x] = in[(size_t)(r0 + i) * C + c0 + threadIdx.x];
  __syncthreads();
#pragma unroll
  for (int i = threadIdx.y; i < 32; i += 8)
    out[(size_t)(c0 + i) * R + r0 + threadIdx.x] = __float2bfloat16(t[threadIdx.x][i]);
}

// fp32 -> bf16 elementwise (4 per thread)
__global__ void cast_bf16(const float* __restrict__ in, bf16* __restrict__ out, int n4) {
  int i = blockIdx.x * 256 + threadIdx.x;
  if (i < n4) {
    float4 v = *(const float4*)(in + i * 4);
    bf16* o = out + i * 4;
    o[0] = __float2bfloat16(v.x); o[1] = __float2bfloat16(v.y);
    o[2] = __float2bfloat16(v.z); o[3] = __float2bfloat16(v.w);
  }
}

// b2w1[h'] = sum_d b2[d] * W1[d][h']. Parallel over d: block = 16 h x 16 d-slices,
// grid 128 blocks (2048/16); LDS reduce over the 16 d-slices.
__global__ void b2w1_kernel(const float* __restrict__ b2, const float* __restrict__ W1,
                            float* __restrict__ out) {
  __shared__ float red[16][17];
  const int hl = threadIdx.x & 15;    // h within group
  const int ds = threadIdx.x >> 4;    // d-slice
  const int h = blockIdx.x * 16 + hl;
  float s = 0.f;
  for (int d = ds * 64; d < ds * 64 + 64; ++d) s += b2[d] * W1[(size_t)d * Hdim + h];
  red[ds][hl] = s;
  __syncthreads();
  if (ds == 0) {
    float t = 0.f;
#pragma unroll
    for (int k = 0; k < 16; ++k) t += red[k][hl];
    out[h] = t;
  }
}

extern "C" void kernel_launch(void* const* d_in, const int* in_sizes, int n_in, void* d_out,
                              int out_size, void* d_ws, size_t ws_size, hipStream_t stream) {
  const float* x = (const float*)d_in[0];
  const float* W1 = (const float*)d_in[1];
  const float* b1 = (const float*)d_in[2];
  const float* W2 = (const float*)d_in[3];
  const float* b2 = (const float*)d_in[4];
  float* y = (float*)d_out;

  char* ws = (char*)d_ws;
  bf16* W1t = (bf16*)(ws + 0);                  // [2048][1024] bf16, 4 MB   (W1^T)
  bf16* W2bf = (bf16*)(ws + (4ull << 20));      // [2048][1024] bf16, 4 MB   (W2 rm)
  bf16* W2t = (bf16*)(ws + (8ull << 20));       // [1024][2048] bf16, 4 MB   (W2^T)
  bf16* W21t = (bf16*)(ws + (12ull << 20));     // [2048][2048] bf16, 8 MB   ((W2@W1)^T)
  bf16* xbf = (bf16*)(ws + (20ull << 20));      // [512][1024] bf16, 1 MB
  bf16* Tbuf = (bf16*)(ws + (21ull << 20));     // [512][2048] bf16, 2 MB
  bf16* Kbuf = (bf16*)(ws + (23ull << 20));     // 5 x MH bf16 (owner layout), 10 MB
  bf16* Gbf = (bf16*)(ws + (33ull << 20));      // [512][2048] bf16, 2 MB (row-major)
  float* yW1 = (float*)(ws + (35ull << 20));    // MH f32 (owner layout), 4 MB
  unsigned short* Gown = (unsigned short*)(ws + (39ull << 20));  // MH bf16 owner, 2 MB
  float* b2w1 = (float*)(ws + (43ull << 20));   // [2048] f32

  GArgs a = {};
  a.b1 = b1; a.b2w1 = b2w1; a.xin = x; a.b2 = b2;
  a.yW1 = yW1; a.T = Tbuf; a.K = Kbuf; a.G = Gown; a.y = y;

  constexpr int SMEM = 131072;
  hipFuncSetAttribute((const void*)&fused_gemm<M_PLAIN, 0, Hdim, 1024>,
                      hipFuncAttributeMaxDynamicSharedMemorySize, SMEM);
  hipFuncSetAttribute((const void*)&fused_gemm<M_INIT, 0, Hdim, 1024>,
                      hipFuncAttributeMaxDynamicSharedMemorySize, SMEM);
  hipFuncSetAttribute((const void*)&fused_gemm<M_STG, 1, Hdim, Hdim>,
                      hipFuncAttributeMaxDynamicSharedMemorySize, SMEM);
  hipFuncSetAttribute((const void*)&fused_gemm<M_STG, 2, Hdim, Hdim>,
                      hipFuncAttributeMaxDynamicSharedMemorySize, SMEM);
  hipFuncSetAttribute((const void*)&fused_gemm<M_STG, 3, Hdim, Hdim>,
                      hipFuncAttributeMaxDynamicSharedMemorySize, SMEM);
  hipFuncSetAttribute((const void*)&fused_gemm<M_STG, 4, Hdim, Hdim>,
                      hipFuncAttributeMaxDynamicSharedMemorySize, SMEM);
  hipFuncSetAttribute((const void*)&fused_gemm<M_STG, 5, Hdim, Hdim>,
                      hipFuncAttributeMaxDynamicSharedMemorySize, SMEM);
  hipFuncSetAttribute((const void*)&fused_gemm<M_STG, 6, Hdim, Hdim>,
                      hipFuncAttributeMaxDynamicSharedMemorySize, SMEM);
  hipFuncSetAttribute((const void*)&fused_gemm<M_FINAL, 0, Ddim, Hdim>,
                      hipFuncAttributeMaxDynamicSharedMemorySize, SMEM);

  // ---- setup (one-time) ----
  transpose_to_bf16<<<dim3(Hdim / 32, Ddim / 32), dim3(32, 8), 0, stream>>>(W1, W1t, Ddim, Hdim);
  transpose_to_bf16<<<dim3(Ddim / 32, Hdim / 32), dim3(32, 8), 0, stream>>>(W2, W2t, Hdim, Ddim);
  cast_bf16<<<(Hdim * Ddim / 4 + 255) / 256, 256, 0, stream>>>(W2, W2bf, Hdim * Ddim / 4);
  cast_bf16<<<(Mdim * Ddim / 4 + 255) / 256, 256, 0, stream>>>(x, xbf, Mdim * Ddim / 4);
  b2w1_kernel<<<Hdim / 16, 256, 0, stream>>>(b2, W1, b2w1);

  // W21t[h'][h] = sum_d W1[d,h']*W2[h,d]  : A=W1t [2048][1024], Bt=W2bf [2048][1024]
  {
    GArgs p = a; p.A = W1t; p.Bt = W2bf; p.Wout = W21t;
    fused_gemm<M_PLAIN, 0, Hdim, 1024><<<32 * 32, 512, SMEM, stream>>>(p);
  }
  // init: yW1 = x@W1 (owner layout) ; T1 = tanh(+b1) ; G = CF5[0]*tanh (owner bf16)
  {
    GArgs p = a; p.A = xbf; p.Bt = W1t;
    fused_gemm<M_INIT, 0, Hdim, 1024><<<8 * 32, 512, SMEM, stream>>>(p);
  }

  // ---- 16 RK steps, one H-space GEMM per stage (skip last step's stage 6) ----
  GArgs sg = a; sg.A = Tbuf; sg.Bt = W21t;
  for (int step = 0; step < 16; ++step) {
    fused_gemm<M_STG, 1, Hdim, Hdim><<<8 * 32, 512, SMEM, stream>>>(sg);
    fused_gemm<M_STG, 2, Hdim, Hdim><<<8 * 32, 512, SMEM, stream>>>(sg);
    fused_gemm<M_STG, 3, Hdim, Hdim><<<8 * 32, 512, SMEM, stream>>>(sg);
    fused_gemm<M_STG, 4, Hdim, Hdim><<<8 * 32, 512, SMEM, stream>>>(sg);
    fused_gemm<M_STG, 5, Hdim, Hdim><<<8 * 32, 512, SMEM, stream>>>(sg);
    if (step < 15)
      fused_gemm<M_STG, 6, Hdim, Hdim><<<8 * 32, 512, SMEM, stream>>>(sg);
  }

  // ---- final: y = x + Gbf@W2 + b2 ----
  gcvt<<<Mdim * (Hdim / 8) / 256, 256, 0, stream>>>(Gown, Gbf);
  {
    GArgs p = a; p.A = Gbf; p.Bt = W2t;
    fused_gemm<M_FINAL, 0, Ddim, Hdim><<<8 * 16, 512, SMEM, stream>>>(p);
  }
}